// Round 2
// baseline (6092.143 us; speedup 1.0000x reference)
//
#include <hip/hip_runtime.h>

// =====================  problem constants  =====================
constexpr int NB = 8;        // batch
constexpr int TSTEPS = 10;   // timesteps

// =====================  workspace layout (bytes)  =====================
constexpr size_t SZ_ME1 = (size_t)NB*32*128*128*4;
constexpr size_t SZ_ME2 = (size_t)NB*64*64*64*4;
constexpr size_t SZ_ME3 = (size_t)NB*128*32*32*4;
constexpr size_t SZ_MD3 = SZ_ME2;
constexpr size_t SZ_MD2 = SZ_ME1;
constexpr size_t SZ_MD1 = (size_t)NB*32*256*256*4;
constexpr size_t SZ_MN1 = SZ_ME1;
constexpr size_t SZ_MN2 = SZ_ME2;

constexpr size_t O_ME1 = 0;
constexpr size_t O_ME2 = O_ME1 + SZ_ME1;
constexpr size_t O_ME3 = O_ME2 + SZ_ME2;
constexpr size_t O_MD3 = O_ME3 + SZ_ME3;
constexpr size_t O_MD2 = O_MD3 + SZ_MD3;
constexpr size_t O_MD1 = O_MD2 + SZ_MD2;
constexpr size_t O_MN1 = O_MD1 + SZ_MD1;
constexpr size_t O_MN2 = O_MN1 + SZ_MN1;
constexpr size_t ZERO_BYTES = O_MN2 + SZ_MN2;   // 146,800,640 B zeroed each launch

constexpr size_t O_S1  = ZERO_BYTES;                       // u8 spikes
constexpr size_t O_S2  = O_S1  + (size_t)NB*32*128*128;
constexpr size_t O_S3  = O_S2  + (size_t)NB*64*64*64;
constexpr size_t O_D3F = O_S3  + (size_t)NB*128*32*32;     // float (spike+skip)
constexpr size_t O_D2F = O_D3F + SZ_MD3;
constexpr size_t O_D1U = O_D2F + SZ_MD2;                   // u8 spikes
constexpr size_t O_EFF3 = O_D1U + (size_t)NB*32*256*256;   // eff tables (float)
constexpr size_t O_EFF2 = O_EFF3 + (size_t)2*64*128*8*4;
constexpr size_t O_EFF1 = O_EFF2 + (size_t)2*32*64*8*4;
constexpr size_t O_WTE1 = O_EFF1 + (size_t)2*32*32*8*4;    // transposed weights
constexpr size_t O_WTE2 = O_WTE1 + (size_t)2*5*5*32*4;
constexpr size_t O_WTE3 = O_WTE2 + (size_t)32*3*3*64*4;
constexpr size_t O_WTFL = O_WTE3 + (size_t)64*3*3*128*4;
constexpr size_t O_WSK2 = O_WTFL + (size_t)32*3*3*2*4;
constexpr size_t O_WSK1 = O_WSK2 + (size_t)64*64*4;
// end: ~188 MiB

// =====================  prepass kernels  =====================
// wT[((ci*K+ky)*K+kx)*OC + oc] = w[((oc*IC+ci)*K+ky)*K+kx]
template<int OC, int IC, int K>
__global__ void k_transpose_w(const float* __restrict__ w, float* __restrict__ wT) {
    int i = blockIdx.x * 256 + threadIdx.x;
    constexpr int total = OC * IC * K * K;
    if (i >= total) return;
    int oc = i % OC; int r = i / OC;
    int kx = r % K;  r /= K;
    int ky = r % K;  r /= K;
    int ci = r;
    wT[i] = w[((oc * IC + ci) * K + ky) * K + kx];
}

// eff[((py*OC+oc)*IC+ci)*8 + (px*4 + di*2 + dj)]
// upsample2-then-conv3x3 collapsed to 2x2 conv per output parity
template<int OC, int IC>
__global__ void k_eff(const float* __restrict__ w, float* __restrict__ eff) {
    int i = blockIdx.x * 256 + threadIdx.x;
    constexpr int total = 2 * OC * IC;
    if (i >= total) return;
    int ci = i % IC; int r = i / IC;
    int oc = r % OC; int py = r / OC;
    const float* wp = w + ((size_t)oc * IC + ci) * 9;
    float w00=wp[0],w01=wp[1],w02=wp[2],w10=wp[3],w11=wp[4],w12=wp[5],w20=wp[6],w21=wp[7],w22=wp[8];
    float r0c0,r0c1,r0c2,r1c0,r1c1,r1c2;
    if (py == 0) { r0c0=w00;     r0c1=w01;     r0c2=w02;     r1c0=w10+w20; r1c1=w11+w21; r1c2=w12+w22; }
    else         { r0c0=w00+w10; r0c1=w01+w11; r0c2=w02+w12; r1c0=w20;     r1c1=w21;     r1c2=w22;     }
    float* e = eff + (size_t)i * 8;
    e[0] = r0c0;        e[1] = r0c1 + r0c2;   // px=0
    e[2] = r1c0;        e[3] = r1c1 + r1c2;
    e[4] = r0c0 + r0c1; e[5] = r0c2;          // px=1
    e[6] = r1c0 + r1c1; e[7] = r1c2;
}

// =====================  encoder layer 1 (5x5 s2 p2, fp32 input)  =====================
__global__ __launch_bounds__(256) void k_e1(
    const float* __restrict__ x, const float* __restrict__ wT, const float* __restrict__ b,
    float* __restrict__ me1, float* __restrict__ mn1, unsigned char* __restrict__ s1,
    int t, float inv)
{
    __shared__ float tile[2 * 35 * 36];
    const int tx = threadIdx.x & 15, ty = threadIdx.x >> 4;
    const int n = blockIdx.z;
    const int oy0 = blockIdx.y * 16, ox0 = blockIdx.x * 16;
    const int iy0 = oy0 * 2 - 2, ix0 = ox0 * 2 - 2;

    for (int e = threadIdx.x; e < 2 * 35 * 35; e += 256) {
        int c = e % 35; int r = (e / 35) % 35; int ci = e / (35 * 35);
        int gy = iy0 + r, gx = ix0 + c;
        float v = 0.f;
        if (gy >= 0 && gy < 256 && gx >= 0 && gx < 256)
            v = x[((((size_t)n * TSTEPS + t) * 2 + ci) * 256 + gy) * 256 + gx];
        tile[(ci * 35 + r) * 36 + c] = v;
    }
    __syncthreads();

    float acc[32];
#pragma unroll
    for (int oc = 0; oc < 32; ++oc) acc[oc] = b[oc];
#pragma unroll
    for (int ci = 0; ci < 2; ++ci)
#pragma unroll
        for (int ky = 0; ky < 5; ++ky)
#pragma unroll
            for (int kx = 0; kx < 5; ++kx) {
                float v = tile[(ci * 35 + ty * 2 + ky) * 36 + tx * 2 + kx];
                const float* wp = wT + ((ci * 5 + ky) * 5 + kx) * 32;
#pragma unroll
                for (int oc = 0; oc < 32; ++oc) acc[oc] = fmaf(v, wp[oc], acc[oc]);
            }

    const int oy = oy0 + ty, ox = ox0 + tx;
#pragma unroll
    for (int oc = 0; oc < 32; ++oc) {
        size_t idx = (((size_t)n * 32 + oc) * 128 + oy) * 128 + ox;
        float mo = me1[idx];
        float m  = mo + (acc[oc] - mo) * 0.5f;
        float s  = (m > 1.0f) ? 1.0f : 0.0f;
        me1[idx] = m - s;
        float mn = mn1[idx];
        mn1[idx] = mn + (s - mn) * inv;
        s1[idx]  = (unsigned char)s;
    }
}

// =====================  encoder stride-2 3x3 conv + LIF (e2/e3)  =====================
template<int IC, int OC, int OUT, int OCCH, bool MEAN>
__global__ __launch_bounds__(256) void k_enc(
    const unsigned char* __restrict__ sin, const float* __restrict__ wT, const float* __restrict__ b,
    float* __restrict__ mem, float* __restrict__ mn, unsigned char* __restrict__ sout, float inv)
{
    constexpr int IN = OUT * 2;
    constexpr int ICCH = 32;
    constexpr int TH = 33, TW = 34;
    __shared__ unsigned char tile[ICCH * TH * TW];
    const int tx = threadIdx.x & 15, ty = threadIdx.x >> 4;
    const int nchunks = OC / OCCH;
    const int zi = blockIdx.z;
    const int n   = zi / nchunks;
    const int ocb = (zi % nchunks) * OCCH;
    const int oy0 = blockIdx.y * 16, ox0 = blockIdx.x * 16;
    const int iy0 = oy0 * 2 - 1, ix0 = ox0 * 2 - 1;

    float acc[OCCH];
#pragma unroll
    for (int oc = 0; oc < OCCH; ++oc) acc[oc] = b[ocb + oc];

    for (int icc = 0; icc < IC; icc += ICCH) {
        __syncthreads();
        for (int e = threadIdx.x; e < ICCH * 33 * 33; e += 256) {
            int c = e % 33; int r = (e / 33) % 33; int ci = e / (33 * 33);
            int gy = iy0 + r, gx = ix0 + c;
            unsigned char v = 0;
            if (gy >= 0 && gy < IN && gx >= 0 && gx < IN)
                v = sin[(((size_t)n * IC + icc + ci) * IN + gy) * IN + gx];
            tile[(ci * TH + r) * TW + c] = v;
        }
        __syncthreads();
#pragma unroll 1
        for (int ci = 0; ci < ICCH; ++ci) {
#pragma unroll
            for (int ky = 0; ky < 3; ++ky)
#pragma unroll
                for (int kx = 0; kx < 3; ++kx) {
                    float v = (float)tile[(ci * TH + ty * 2 + ky) * TW + tx * 2 + kx];
                    const float* wp = wT + (((icc + ci) * 3 + ky) * 3 + kx) * OC + ocb;
#pragma unroll
                    for (int oc = 0; oc < OCCH; ++oc) acc[oc] = fmaf(v, wp[oc], acc[oc]);
                }
        }
    }

    const int oy = oy0 + ty, ox = ox0 + tx;
#pragma unroll
    for (int oc = 0; oc < OCCH; ++oc) {
        size_t idx = (((size_t)n * OC + ocb + oc) * OUT + oy) * OUT + ox;
        float mo = mem[idx];
        float m  = mo + (acc[oc] - mo) * 0.5f;
        float s  = (m > 1.0f) ? 1.0f : 0.0f;
        mem[idx] = m - s;
        if constexpr (MEAN) { float mv = mn[idx]; mn[idx] = mv + (s - mv) * inv; }
        sout[idx] = (unsigned char)s;
    }
}

// =====================  decoder: upsample2 + conv3x3 + LIF (+1x1 skip)  =====================
// Parity decomposition: block handles one row-parity plane; each thread computes the
// (even,odd) column pair -> float2-coalesced membrane/output access, wave-uniform eff weights.
// store_out==0 skips the spike store (d1 for t<9: spikes feed only the final flow conv).
template<int IC, int OC, int SRC, int OCCH, int ICCH, bool SKIP, bool SRCU8, bool OUTU8>
__global__ __launch_bounds__(256) void k_dec(
    const void* __restrict__ srcv, const float* __restrict__ eff, const float* __restrict__ b,
    float* __restrict__ mem, const float* __restrict__ mnsk, const float* __restrict__ wskT,
    void* __restrict__ outv, int store_out)
{
    constexpr int OUT = SRC * 2;
    constexpr int TH = 17, TW = 18;
    __shared__ __align__(16) unsigned char smem[ICCH * TH * TW * (SRCU8 ? 1 : 4)];
    unsigned char* tileB = smem;
    float* tileF = (float*)smem;
    const unsigned char* src8 = (const unsigned char*)srcv;
    const float* srcF = (const float*)srcv;

    const int tx = threadIdx.x & 15, ty = threadIdx.x >> 4;
    constexpr int nchunks = OC / OCCH;
    int zi = blockIdx.z;
    const int ocb = (zi % nchunks) * OCCH; zi /= nchunks;
    const int py = zi & 1;
    const int n  = zi >> 1;
    const int i0 = blockIdx.y * 16;   // plane-row base
    const int j0 = blockIdx.x * 16;   // plane-col base (each thread col = 2 out cols)
    const int rbase0 = i0 - 1 + py;
    const int cbase0 = j0 - 1;

    float accA[OCCH], accB[OCCH];
#pragma unroll
    for (int oc = 0; oc < OCCH; ++oc) { accA[oc] = 0.f; accB[oc] = 0.f; }

    for (int icc = 0; icc < IC; icc += ICCH) {
        __syncthreads();
        for (int e = threadIdx.x; e < ICCH * TH * TW; e += 256) {
            int c = e % TW; int r = (e / TW) % TH; int ci = e / (TH * TW);
            int gy = rbase0 + r, gx = cbase0 + c;
            bool ok = (gy >= 0 && gy < SRC && gx >= 0 && gx < SRC);
            size_t gidx = (((size_t)n * IC + icc + ci) * SRC + gy) * SRC + gx;
            if constexpr (SRCU8) tileB[e] = ok ? src8[gidx] : (unsigned char)0;
            else                 tileF[e] = ok ? srcF[gidx] : 0.f;
        }
        __syncthreads();
#pragma unroll 1
        for (int ci = 0; ci < ICCH; ++ci) {
            float s00, s01, s02, s10, s11, s12;
            const int base = (ci * TH + ty) * TW + tx;
            if constexpr (SRCU8) {
                s00 = (float)tileB[base];      s01 = (float)tileB[base + 1];      s02 = (float)tileB[base + 2];
                s10 = (float)tileB[base + TW]; s11 = (float)tileB[base + TW + 1]; s12 = (float)tileB[base + TW + 2];
            } else {
                s00 = tileF[base];      s01 = tileF[base + 1];      s02 = tileF[base + 2];
                s10 = tileF[base + TW]; s11 = tileF[base + TW + 1]; s12 = tileF[base + TW + 2];
            }
#pragma unroll
            for (int oc = 0; oc < OCCH; ++oc) {
                const float* e8 = eff + ((((size_t)py * OC + ocb + oc) * IC) + icc + ci) * 8;
                accA[oc] = fmaf(s00, e8[0], accA[oc]);
                accA[oc] = fmaf(s01, e8[1], accA[oc]);
                accA[oc] = fmaf(s10, e8[2], accA[oc]);
                accA[oc] = fmaf(s11, e8[3], accA[oc]);
                accB[oc] = fmaf(s01, e8[4], accB[oc]);
                accB[oc] = fmaf(s02, e8[5], accB[oc]);
                accB[oc] = fmaf(s11, e8[6], accB[oc]);
                accB[oc] = fmaf(s12, e8[7], accB[oc]);
            }
        }
    }

    const int oy  = 2 * (i0 + ty) + py;
    const int ox0 = 2 * (j0 + tx);

    // LIF (soft reset); spike values left in accA/accB
#pragma unroll
    for (int oc = 0; oc < OCCH; ++oc) {
        int ocg = ocb + oc;
        size_t idx = (((size_t)n * OC + ocg) * OUT + oy) * OUT + ox0;
        float2 mv = *(const float2*)(mem + idx);
        float bb = b[ocg];
        float cA = accA[oc] + bb, cB = accB[oc] + bb;
        float mA = mv.x + (cA - mv.x) * 0.5f;
        float mB = mv.y + (cB - mv.y) * 0.5f;
        float sA = (mA > 1.f) ? 1.f : 0.f;
        float sB = (mB > 1.f) ? 1.f : 0.f;
        *(float2*)(mem + idx) = make_float2(mA - sA, mB - sB);
        accA[oc] = sA; accB[oc] = sB;
    }

    if constexpr (SKIP) {   // 1x1 conv over running mean, added AFTER spike
#pragma unroll 1
        for (int ci = 0; ci < OC; ++ci) {
            size_t sidx = (((size_t)n * OC + ci) * OUT + oy) * OUT + ox0;
            float2 v = *(const float2*)(mnsk + sidx);
            const float* wp = wskT + ci * OC + ocb;
#pragma unroll
            for (int oc = 0; oc < OCCH; ++oc) {
                accA[oc] = fmaf(v.x, wp[oc], accA[oc]);
                accB[oc] = fmaf(v.y, wp[oc], accB[oc]);
            }
        }
    }

    if (store_out) {
#pragma unroll
        for (int oc = 0; oc < OCCH; ++oc) {
            int ocg = ocb + oc;
            size_t idx = (((size_t)n * OC + ocg) * OUT + oy) * OUT + ox0;
            if constexpr (OUTU8) {
                unsigned char* o8 = (unsigned char*)outv;
                o8[idx]     = (unsigned char)accA[oc];
                o8[idx + 1] = (unsigned char)accB[oc];
            } else {
                *(float2*)((float*)outv + idx) = make_float2(accA[oc], accB[oc]);
            }
        }
    }
}

// =====================  final flow conv (3x3 s1 p1, 32->2, *16)  =====================
__global__ __launch_bounds__(256) void k_flow(
    const unsigned char* __restrict__ d1, const float* __restrict__ wT, const float* __restrict__ b,
    float* __restrict__ out)
{
    constexpr int HW = 256;
    __shared__ unsigned char tile[32 * 18 * 19];
    const int tx = threadIdx.x & 15, ty = threadIdx.x >> 4;
    const int n = blockIdx.z;
    const int oy0 = blockIdx.y * 16, ox0 = blockIdx.x * 16;

    for (int e = threadIdx.x; e < 32 * 18 * 18; e += 256) {
        int c = e % 18; int r = (e / 18) % 18; int ci = e / (18 * 18);
        int gy = oy0 - 1 + r, gx = ox0 - 1 + c;
        unsigned char v = 0;
        if (gy >= 0 && gy < HW && gx >= 0 && gx < HW)
            v = d1[(((size_t)n * 32 + ci) * HW + gy) * HW + gx];
        tile[(ci * 18 + r) * 19 + c] = v;
    }
    __syncthreads();

    float a0 = b[0], a1 = b[1];
#pragma unroll 1
    for (int ci = 0; ci < 32; ++ci)
#pragma unroll
        for (int ky = 0; ky < 3; ++ky)
#pragma unroll
            for (int kx = 0; kx < 3; ++kx) {
                float v = (float)tile[(ci * 18 + ty + ky) * 19 + tx + kx];
                const float* wp = wT + ((ci * 3 + ky) * 3 + kx) * 2;
                a0 = fmaf(v, wp[0], a0);
                a1 = fmaf(v, wp[1], a1);
            }

    const int oy = oy0 + ty, ox = ox0 + tx;
    out[(((size_t)n * 2 + 0) * HW + oy) * HW + ox] = a0 * 16.f;
    out[(((size_t)n * 2 + 1) * HW + oy) * HW + ox] = a1 * 16.f;
}

// =====================  launch  =====================
extern "C" void kernel_launch(void* const* d_in, const int* in_sizes, int n_in,
                              void* d_out, int out_size, void* d_ws, size_t ws_size,
                              hipStream_t stream)
{
    const float* x     = (const float*)d_in[0];
    const float* w_e1  = (const float*)d_in[1];
    const float* b_e1  = (const float*)d_in[2];
    const float* w_e2  = (const float*)d_in[3];
    const float* b_e2  = (const float*)d_in[4];
    const float* w_e3  = (const float*)d_in[5];
    const float* b_e3  = (const float*)d_in[6];
    const float* w_d3  = (const float*)d_in[7];
    const float* b_d3  = (const float*)d_in[8];
    const float* w_d2  = (const float*)d_in[9];
    const float* b_d2  = (const float*)d_in[10];
    const float* w_d1  = (const float*)d_in[11];
    const float* b_d1  = (const float*)d_in[12];
    const float* w_sk2 = (const float*)d_in[13];
    const float* w_sk1 = (const float*)d_in[14];
    const float* w_fl  = (const float*)d_in[15];
    const float* b_fl  = (const float*)d_in[16];

    char* ws = (char*)d_ws;
    float* me1 = (float*)(ws + O_ME1);
    float* me2 = (float*)(ws + O_ME2);
    float* me3 = (float*)(ws + O_ME3);
    float* md3 = (float*)(ws + O_MD3);
    float* md2 = (float*)(ws + O_MD2);
    float* md1 = (float*)(ws + O_MD1);
    float* mn1 = (float*)(ws + O_MN1);
    float* mn2 = (float*)(ws + O_MN2);
    unsigned char* s1  = (unsigned char*)(ws + O_S1);
    unsigned char* s2  = (unsigned char*)(ws + O_S2);
    unsigned char* s3  = (unsigned char*)(ws + O_S3);
    float* d3f = (float*)(ws + O_D3F);
    float* d2f = (float*)(ws + O_D2F);
    unsigned char* d1u = (unsigned char*)(ws + O_D1U);
    float* eff3 = (float*)(ws + O_EFF3);
    float* eff2 = (float*)(ws + O_EFF2);
    float* eff1 = (float*)(ws + O_EFF1);
    float* wTe1 = (float*)(ws + O_WTE1);
    float* wTe2 = (float*)(ws + O_WTE2);
    float* wTe3 = (float*)(ws + O_WTE3);
    float* wTfl = (float*)(ws + O_WTFL);
    float* wsk2 = (float*)(ws + O_WSK2);
    float* wsk1 = (float*)(ws + O_WSK1);

    // zero all membrane / running-mean state (ws is poisoned before every call)
    hipMemsetAsync(d_ws, 0, ZERO_BYTES, stream);

    // prepass: weight transposes + effective upsample-conv weight tables
    k_transpose_w<32, 2, 5><<<(1600 + 255) / 256, 256, 0, stream>>>(w_e1, wTe1);
    k_transpose_w<64, 32, 3><<<(18432 + 255) / 256, 256, 0, stream>>>(w_e2, wTe2);
    k_transpose_w<128, 64, 3><<<(73728 + 255) / 256, 256, 0, stream>>>(w_e3, wTe3);
    k_transpose_w<2, 32, 3><<<(576 + 255) / 256, 256, 0, stream>>>(w_fl, wTfl);
    k_transpose_w<64, 64, 1><<<(4096 + 255) / 256, 256, 0, stream>>>(w_sk2, wsk2);
    k_transpose_w<32, 32, 1><<<(1024 + 255) / 256, 256, 0, stream>>>(w_sk1, wsk1);
    k_eff<64, 128><<<(2 * 64 * 128 + 255) / 256, 256, 0, stream>>>(w_d3, eff3);
    k_eff<32, 64><<<(2 * 32 * 64 + 255) / 256, 256, 0, stream>>>(w_d2, eff2);
    k_eff<32, 32><<<(2 * 32 * 32 + 255) / 256, 256, 0, stream>>>(w_d1, eff1);

    for (int t = 0; t < TSTEPS; ++t) {
        float inv = 1.0f / (float)(t + 1);
        k_e1<<<dim3(8, 8, NB), 256, 0, stream>>>(x, wTe1, b_e1, me1, mn1, s1, t, inv);
        k_enc<32, 64, 64, 16, true><<<dim3(4, 4, NB * 4), 256, 0, stream>>>(
            s1, wTe2, b_e2, me2, mn2, s2, inv);
        k_enc<64, 128, 32, 16, false><<<dim3(2, 2, NB * 8), 256, 0, stream>>>(
            s2, wTe3, b_e3, me3, (float*)nullptr, s3, 0.f);
        k_dec<128, 64, 32, 16, 128, true, true, false><<<dim3(2, 2, NB * 2 * 4), 256, 0, stream>>>(
            s3, eff3, b_d3, md3, mn2, wsk2, d3f, 1);
        k_dec<64, 32, 64, 16, 32, true, false, false><<<dim3(4, 4, NB * 2 * 2), 256, 0, stream>>>(
            d3f, eff2, b_d2, md2, mn1, wsk1, d2f, 1);
        k_dec<32, 32, 128, 16, 32, false, false, true><<<dim3(8, 8, NB * 2 * 2), 256, 0, stream>>>(
            d2f, eff1, b_d1, md1, (const float*)nullptr, (const float*)nullptr, d1u,
            (t == TSTEPS - 1) ? 1 : 0);
    }
    k_flow<<<dim3(16, 16, NB), 256, 0, stream>>>(d1u, wTfl, b_fl, (float*)d_out);
}

// Round 6
// 6033.311 us; speedup vs baseline: 1.0098x; 1.0098x over previous
//
#include <hip/hip_runtime.h>

// =====================  problem constants  =====================
constexpr int NB = 8;        // batch
constexpr int TSTEPS = 10;   // timesteps

// =====================  workspace layout (bytes)  =====================
constexpr size_t SZ_ME1 = (size_t)NB*32*128*128*4;
constexpr size_t SZ_ME2 = (size_t)NB*64*64*64*4;
constexpr size_t SZ_ME3 = (size_t)NB*128*32*32*4;
constexpr size_t SZ_MD3 = SZ_ME2;
constexpr size_t SZ_MD2 = SZ_ME1;
constexpr size_t SZ_MD1 = (size_t)NB*32*256*256*4;
constexpr size_t SZ_MN1 = SZ_ME1;
constexpr size_t SZ_MN2 = SZ_ME2;

constexpr size_t O_ME1 = 0;
constexpr size_t O_ME2 = O_ME1 + SZ_ME1;
constexpr size_t O_ME3 = O_ME2 + SZ_ME2;
constexpr size_t O_MD3 = O_ME3 + SZ_ME3;
constexpr size_t O_MD2 = O_MD3 + SZ_MD3;
constexpr size_t O_MD1 = O_MD2 + SZ_MD2;
constexpr size_t O_MN1 = O_MD1 + SZ_MD1;
constexpr size_t O_MN2 = O_MN1 + SZ_MN1;
constexpr size_t ZERO_BYTES = O_MN2 + SZ_MN2;   // 146,800,640 B zeroed each launch

constexpr size_t O_S1  = ZERO_BYTES;                       // u8 spikes
constexpr size_t O_S2  = O_S1  + (size_t)NB*32*128*128;
constexpr size_t O_S3  = O_S2  + (size_t)NB*64*64*64;
constexpr size_t O_D3F = O_S3  + (size_t)NB*128*32*32;     // float (spike+skip)
constexpr size_t O_D2F = O_D3F + SZ_MD3;
constexpr size_t O_D1U = O_D2F + SZ_MD2;                   // u8 spikes
constexpr size_t O_EFF3 = O_D1U + (size_t)NB*32*256*256;   // eff tables (float)
constexpr size_t O_EFF2 = O_EFF3 + (size_t)2*64*128*8*4;
constexpr size_t O_EFF1 = O_EFF2 + (size_t)2*32*64*8*4;
constexpr size_t O_WTE1 = O_EFF1 + (size_t)2*32*32*8*4;    // transposed weights
constexpr size_t O_WTE2 = O_WTE1 + (size_t)2*5*5*32*4;
constexpr size_t O_WTE3 = O_WTE2 + (size_t)32*3*3*64*4;
constexpr size_t O_WTFL = O_WTE3 + (size_t)64*3*3*128*4;
constexpr size_t O_WSK2 = O_WTFL + (size_t)32*3*3*2*4;
constexpr size_t O_WSK1 = O_WSK2 + (size_t)64*64*4;
// end: ~188 MiB

// =====================  prepass kernels  =====================
// wT[((ci*K+ky)*K+kx)*OC + oc] = w[((oc*IC+ci)*K+ky)*K+kx]
template<int OC, int IC, int K>
__global__ void k_transpose_w(const float* __restrict__ w, float* __restrict__ wT) {
    int i = blockIdx.x * 256 + threadIdx.x;
    constexpr int total = OC * IC * K * K;
    if (i >= total) return;
    int oc = i % OC; int r = i / OC;
    int kx = r % K;  r /= K;
    int ky = r % K;  r /= K;
    int ci = r;
    wT[i] = w[((oc * IC + ci) * K + ky) * K + kx];
}

// eff[((py*OC+oc)*IC+ci)*8 + (px*4 + di*2 + dj)]
// upsample2-then-conv3x3 collapsed to 2x2 conv per output parity
template<int OC, int IC>
__global__ void k_eff(const float* __restrict__ w, float* __restrict__ eff) {
    int i = blockIdx.x * 256 + threadIdx.x;
    constexpr int total = 2 * OC * IC;
    if (i >= total) return;
    int ci = i % IC; int r = i / IC;
    int oc = r % OC; int py = r / OC;
    const float* wp = w + ((size_t)oc * IC + ci) * 9;
    float w00=wp[0],w01=wp[1],w02=wp[2],w10=wp[3],w11=wp[4],w12=wp[5],w20=wp[6],w21=wp[7],w22=wp[8];
    float r0c0,r0c1,r0c2,r1c0,r1c1,r1c2;
    if (py == 0) { r0c0=w00;     r0c1=w01;     r0c2=w02;     r1c0=w10+w20; r1c1=w11+w21; r1c2=w12+w22; }
    else         { r0c0=w00+w10; r0c1=w01+w11; r0c2=w02+w12; r1c0=w20;     r1c1=w21;     r1c2=w22;     }
    float* e = eff + (size_t)i * 8;
    e[0] = r0c0;        e[1] = r0c1 + r0c2;   // px=0
    e[2] = r1c0;        e[3] = r1c1 + r1c2;
    e[4] = r0c0 + r0c1; e[5] = r0c2;          // px=1
    e[6] = r1c0 + r1c1; e[7] = r1c2;
}

// =====================  encoder layer 1 (5x5 s2 p2, fp32 input)  =====================
template<int OCCH>
__global__ __launch_bounds__(256) void k_e1(
    const float* __restrict__ x, const float* __restrict__ wT, const float* __restrict__ b,
    float* __restrict__ me1, float* __restrict__ mn1, unsigned char* __restrict__ s1,
    int t, float inv)
{
    __shared__ float tile[2 * 35 * 36];
    const int tx = threadIdx.x & 15, ty = threadIdx.x >> 4;
    constexpr int nchunks = 32 / OCCH;
    int zi = blockIdx.z;
    const int ocb = (zi % nchunks) * OCCH;
    const int n = zi / nchunks;
    const int oy0 = blockIdx.y * 16, ox0 = blockIdx.x * 16;
    const int iy0 = oy0 * 2 - 2, ix0 = ox0 * 2 - 2;

    for (int e = threadIdx.x; e < 2 * 35 * 35; e += 256) {
        int c = e % 35; int r = (e / 35) % 35; int ci = e / (35 * 35);
        int gy = iy0 + r, gx = ix0 + c;
        float v = 0.f;
        if (gy >= 0 && gy < 256 && gx >= 0 && gx < 256)
            v = x[((((size_t)n * TSTEPS + t) * 2 + ci) * 256 + gy) * 256 + gx];
        tile[(ci * 35 + r) * 36 + c] = v;
    }
    __syncthreads();

    float acc[OCCH];
#pragma unroll
    for (int oc = 0; oc < OCCH; ++oc) acc[oc] = b[ocb + oc];
#pragma unroll
    for (int ci = 0; ci < 2; ++ci)
#pragma unroll
        for (int ky = 0; ky < 5; ++ky)
#pragma unroll
            for (int kx = 0; kx < 5; ++kx) {
                float v = tile[(ci * 35 + ty * 2 + ky) * 36 + tx * 2 + kx];
                const float* wp = wT + ((ci * 5 + ky) * 5 + kx) * 32 + ocb;
#pragma unroll
                for (int oc = 0; oc < OCCH; ++oc) acc[oc] = fmaf(v, wp[oc], acc[oc]);
            }

    const int oy = oy0 + ty, ox = ox0 + tx;
#pragma unroll
    for (int oc = 0; oc < OCCH; ++oc) {
        size_t idx = (((size_t)n * 32 + ocb + oc) * 128 + oy) * 128 + ox;
        float mo = me1[idx];
        float m  = mo + (acc[oc] - mo) * 0.5f;
        float s  = (m > 1.0f) ? 1.0f : 0.0f;
        me1[idx] = m - s;
        float mn = mn1[idx];
        mn1[idx] = mn + (s - mn) * inv;
        s1[idx]  = (unsigned char)s;
    }
}

// =====================  encoder stride-2 3x3 conv + LIF (e2/e3)  =====================
template<int IC, int OC, int OUT, int OCCH, bool MEAN>
__global__ __launch_bounds__(256) void k_enc(
    const unsigned char* __restrict__ sin, const float* __restrict__ wT, const float* __restrict__ b,
    float* __restrict__ mem, float* __restrict__ mn, unsigned char* __restrict__ sout, float inv)
{
    constexpr int IN = OUT * 2;
    constexpr int ICCH = 32;
    constexpr int TH = 33, TW = 34;
    __shared__ unsigned char tile[ICCH * TH * TW];
    const int tx = threadIdx.x & 15, ty = threadIdx.x >> 4;
    const int nchunks = OC / OCCH;
    const int zi = blockIdx.z;
    const int n   = zi / nchunks;
    const int ocb = (zi % nchunks) * OCCH;
    const int oy0 = blockIdx.y * 16, ox0 = blockIdx.x * 16;
    const int iy0 = oy0 * 2 - 1, ix0 = ox0 * 2 - 1;

    float acc[OCCH];
#pragma unroll
    for (int oc = 0; oc < OCCH; ++oc) acc[oc] = b[ocb + oc];

    for (int icc = 0; icc < IC; icc += ICCH) {
        __syncthreads();
        for (int e = threadIdx.x; e < ICCH * 33 * 33; e += 256) {
            int c = e % 33; int r = (e / 33) % 33; int ci = e / (33 * 33);
            int gy = iy0 + r, gx = ix0 + c;
            unsigned char v = 0;
            if (gy >= 0 && gy < IN && gx >= 0 && gx < IN)
                v = sin[(((size_t)n * IC + icc + ci) * IN + gy) * IN + gx];
            tile[(ci * TH + r) * TW + c] = v;
        }
        __syncthreads();
#pragma unroll 1
        for (int ci = 0; ci < ICCH; ++ci) {
#pragma unroll
            for (int ky = 0; ky < 3; ++ky)
#pragma unroll
                for (int kx = 0; kx < 3; ++kx) {
                    float v = (float)tile[(ci * TH + ty * 2 + ky) * TW + tx * 2 + kx];
                    const float* wp = wT + (((icc + ci) * 3 + ky) * 3 + kx) * OC + ocb;
#pragma unroll
                    for (int oc = 0; oc < OCCH; ++oc) acc[oc] = fmaf(v, wp[oc], acc[oc]);
                }
        }
    }

    const int oy = oy0 + ty, ox = ox0 + tx;
#pragma unroll
    for (int oc = 0; oc < OCCH; ++oc) {
        size_t idx = (((size_t)n * OC + ocb + oc) * OUT + oy) * OUT + ox;
        float mo = mem[idx];
        float m  = mo + (acc[oc] - mo) * 0.5f;
        float s  = (m > 1.0f) ? 1.0f : 0.0f;
        mem[idx] = m - s;
        if constexpr (MEAN) { float mv = mn[idx]; mn[idx] = mv + (s - mv) * inv; }
        sout[idx] = (unsigned char)s;
    }
}

// =====================  decoder: upsample2 + conv3x3 + LIF (+1x1 skip)  =====================
// Parity decomposition: block handles one row-parity plane; each thread computes the
// (even,odd) column pair -> float2-coalesced membrane/output access, wave-uniform eff weights.
// store_out==0 skips the spike store (d1 for t<9: spikes feed only the final flow conv).
template<int IC, int OC, int SRC, int OCCH, int ICCH, bool SKIP, bool SRCU8, bool OUTU8>
__global__ __launch_bounds__(256) void k_dec(
    const void* __restrict__ srcv, const float* __restrict__ eff, const float* __restrict__ b,
    float* __restrict__ mem, const float* __restrict__ mnsk, const float* __restrict__ wskT,
    void* __restrict__ outv, int store_out)
{
    constexpr int OUT = SRC * 2;
    constexpr int TH = 17, TW = 18;
    __shared__ __align__(16) unsigned char smem[ICCH * TH * TW * (SRCU8 ? 1 : 4)];
    unsigned char* tileB = smem;
    float* tileF = (float*)smem;
    const unsigned char* src8 = (const unsigned char*)srcv;
    const float* srcF = (const float*)srcv;

    const int tx = threadIdx.x & 15, ty = threadIdx.x >> 4;
    constexpr int nchunks = OC / OCCH;
    int zi = blockIdx.z;
    const int ocb = (zi % nchunks) * OCCH; zi /= nchunks;
    const int py = zi & 1;
    const int n  = zi >> 1;
    const int i0 = blockIdx.y * 16;   // plane-row base
    const int j0 = blockIdx.x * 16;   // plane-col base (each thread col = 2 out cols)
    const int rbase0 = i0 - 1 + py;
    const int cbase0 = j0 - 1;

    float accA[OCCH], accB[OCCH];
#pragma unroll
    for (int oc = 0; oc < OCCH; ++oc) { accA[oc] = 0.f; accB[oc] = 0.f; }

    for (int icc = 0; icc < IC; icc += ICCH) {
        __syncthreads();
        for (int e = threadIdx.x; e < ICCH * TH * TW; e += 256) {
            int c = e % TW; int r = (e / TW) % TH; int ci = e / (TH * TW);
            int gy = rbase0 + r, gx = cbase0 + c;
            bool ok = (gy >= 0 && gy < SRC && gx >= 0 && gx < SRC);
            size_t gidx = (((size_t)n * IC + icc + ci) * SRC + gy) * SRC + gx;
            if constexpr (SRCU8) tileB[e] = ok ? src8[gidx] : (unsigned char)0;
            else                 tileF[e] = ok ? srcF[gidx] : 0.f;
        }
        __syncthreads();
#pragma unroll 1
        for (int ci = 0; ci < ICCH; ++ci) {
            float s00, s01, s02, s10, s11, s12;
            const int base = (ci * TH + ty) * TW + tx;
            if constexpr (SRCU8) {
                s00 = (float)tileB[base];      s01 = (float)tileB[base + 1];      s02 = (float)tileB[base + 2];
                s10 = (float)tileB[base + TW]; s11 = (float)tileB[base + TW + 1]; s12 = (float)tileB[base + TW + 2];
            } else {
                s00 = tileF[base];      s01 = tileF[base + 1];      s02 = tileF[base + 2];
                s10 = tileF[base + TW]; s11 = tileF[base + TW + 1]; s12 = tileF[base + TW + 2];
            }
#pragma unroll
            for (int oc = 0; oc < OCCH; ++oc) {
                const float* e8 = eff + ((((size_t)py * OC + ocb + oc) * IC) + icc + ci) * 8;
                accA[oc] = fmaf(s00, e8[0], accA[oc]);
                accA[oc] = fmaf(s01, e8[1], accA[oc]);
                accA[oc] = fmaf(s10, e8[2], accA[oc]);
                accA[oc] = fmaf(s11, e8[3], accA[oc]);
                accB[oc] = fmaf(s01, e8[4], accB[oc]);
                accB[oc] = fmaf(s02, e8[5], accB[oc]);
                accB[oc] = fmaf(s11, e8[6], accB[oc]);
                accB[oc] = fmaf(s12, e8[7], accB[oc]);
            }
        }
    }

    const int oy  = 2 * (i0 + ty) + py;
    const int ox0 = 2 * (j0 + tx);

    // LIF (soft reset); spike values left in accA/accB
#pragma unroll
    for (int oc = 0; oc < OCCH; ++oc) {
        int ocg = ocb + oc;
        size_t idx = (((size_t)n * OC + ocg) * OUT + oy) * OUT + ox0;
        float2 mv = *(const float2*)(mem + idx);
        float bb = b[ocg];
        float cA = accA[oc] + bb, cB = accB[oc] + bb;
        float mA = mv.x + (cA - mv.x) * 0.5f;
        float mB = mv.y + (cB - mv.y) * 0.5f;
        float sA = (mA > 1.f) ? 1.f : 0.f;
        float sB = (mB > 1.f) ? 1.f : 0.f;
        *(float2*)(mem + idx) = make_float2(mA - sA, mB - sB);
        accA[oc] = sA; accB[oc] = sB;
    }

    if constexpr (SKIP) {   // 1x1 conv over running mean, added AFTER spike
#pragma unroll 1
        for (int ci = 0; ci < OC; ++ci) {
            size_t sidx = (((size_t)n * OC + ci) * OUT + oy) * OUT + ox0;
            float2 v = *(const float2*)(mnsk + sidx);
            const float* wp = wskT + ci * OC + ocb;
#pragma unroll
            for (int oc = 0; oc < OCCH; ++oc) {
                accA[oc] = fmaf(v.x, wp[oc], accA[oc]);
                accB[oc] = fmaf(v.y, wp[oc], accB[oc]);
            }
        }
    }

    if (store_out) {
#pragma unroll
        for (int oc = 0; oc < OCCH; ++oc) {
            int ocg = ocb + oc;
            size_t idx = (((size_t)n * OC + ocg) * OUT + oy) * OUT + ox0;
            if constexpr (OUTU8) {
                unsigned char* o8 = (unsigned char*)outv;
                o8[idx]     = (unsigned char)accA[oc];
                o8[idx + 1] = (unsigned char)accB[oc];
            } else {
                *(float2*)((float*)outv + idx) = make_float2(accA[oc], accB[oc]);
            }
        }
    }
}

// =====================  final flow conv (3x3 s1 p1, 32->2, *16)  =====================
__global__ __launch_bounds__(256) void k_flow(
    const unsigned char* __restrict__ d1, const float* __restrict__ wT, const float* __restrict__ b,
    float* __restrict__ out)
{
    constexpr int HW = 256;
    __shared__ unsigned char tile[32 * 18 * 19];
    const int tx = threadIdx.x & 15, ty = threadIdx.x >> 4;
    const int n = blockIdx.z;
    const int oy0 = blockIdx.y * 16, ox0 = blockIdx.x * 16;

    for (int e = threadIdx.x; e < 32 * 18 * 18; e += 256) {
        int c = e % 18; int r = (e / 18) % 18; int ci = e / (18 * 18);
        int gy = oy0 - 1 + r, gx = ox0 - 1 + c;
        unsigned char v = 0;
        if (gy >= 0 && gy < HW && gx >= 0 && gx < HW)
            v = d1[(((size_t)n * 32 + ci) * HW + gy) * HW + gx];
        tile[(ci * 18 + r) * 19 + c] = v;
    }
    __syncthreads();

    float a0 = b[0], a1 = b[1];
#pragma unroll 1
    for (int ci = 0; ci < 32; ++ci)
#pragma unroll
        for (int ky = 0; ky < 3; ++ky)
#pragma unroll
            for (int kx = 0; kx < 3; ++kx) {
                float v = (float)tile[(ci * 18 + ty + ky) * 19 + tx + kx];
                const float* wp = wT + ((ci * 3 + ky) * 3 + kx) * 2;
                a0 = fmaf(v, wp[0], a0);
                a1 = fmaf(v, wp[1], a1);
            }

    const int oy = oy0 + ty, ox = ox0 + tx;
    out[(((size_t)n * 2 + 0) * HW + oy) * HW + ox] = a0 * 16.f;
    out[(((size_t)n * 2 + 1) * HW + oy) * HW + ox] = a1 * 16.f;
}

// =====================  launch  =====================
extern "C" void kernel_launch(void* const* d_in, const int* in_sizes, int n_in,
                              void* d_out, int out_size, void* d_ws, size_t ws_size,
                              hipStream_t stream)
{
    const float* x     = (const float*)d_in[0];
    const float* w_e1  = (const float*)d_in[1];
    const float* b_e1  = (const float*)d_in[2];
    const float* w_e2  = (const float*)d_in[3];
    const float* b_e2  = (const float*)d_in[4];
    const float* w_e3  = (const float*)d_in[5];
    const float* b_e3  = (const float*)d_in[6];
    const float* w_d3  = (const float*)d_in[7];
    const float* b_d3  = (const float*)d_in[8];
    const float* w_d2  = (const float*)d_in[9];
    const float* b_d2  = (const float*)d_in[10];
    const float* w_d1  = (const float*)d_in[11];
    const float* b_d1  = (const float*)d_in[12];
    const float* w_sk2 = (const float*)d_in[13];
    const float* w_sk1 = (const float*)d_in[14];
    const float* w_fl  = (const float*)d_in[15];
    const float* b_fl  = (const float*)d_in[16];

    char* ws = (char*)d_ws;
    float* me1 = (float*)(ws + O_ME1);
    float* me2 = (float*)(ws + O_ME2);
    float* me3 = (float*)(ws + O_ME3);
    float* md3 = (float*)(ws + O_MD3);
    float* md2 = (float*)(ws + O_MD2);
    float* md1 = (float*)(ws + O_MD1);
    float* mn1 = (float*)(ws + O_MN1);
    float* mn2 = (float*)(ws + O_MN2);
    unsigned char* s1  = (unsigned char*)(ws + O_S1);
    unsigned char* s2  = (unsigned char*)(ws + O_S2);
    unsigned char* s3  = (unsigned char*)(ws + O_S3);
    float* d3f = (float*)(ws + O_D3F);
    float* d2f = (float*)(ws + O_D2F);
    unsigned char* d1u = (unsigned char*)(ws + O_D1U);
    float* eff3 = (float*)(ws + O_EFF3);
    float* eff2 = (float*)(ws + O_EFF2);
    float* eff1 = (float*)(ws + O_EFF1);
    float* wTe1 = (float*)(ws + O_WTE1);
    float* wTe2 = (float*)(ws + O_WTE2);
    float* wTe3 = (float*)(ws + O_WTE3);
    float* wTfl = (float*)(ws + O_WTFL);
    float* wsk2 = (float*)(ws + O_WSK2);
    float* wsk1 = (float*)(ws + O_WSK1);

    // zero all membrane / running-mean state (ws is poisoned before every call)
    hipMemsetAsync(d_ws, 0, ZERO_BYTES, stream);

    // prepass: weight transposes + effective upsample-conv weight tables
    k_transpose_w<32, 2, 5><<<(1600 + 255) / 256, 256, 0, stream>>>(w_e1, wTe1);
    k_transpose_w<64, 32, 3><<<(18432 + 255) / 256, 256, 0, stream>>>(w_e2, wTe2);
    k_transpose_w<128, 64, 3><<<(73728 + 255) / 256, 256, 0, stream>>>(w_e3, wTe3);
    k_transpose_w<2, 32, 3><<<(576 + 255) / 256, 256, 0, stream>>>(w_fl, wTfl);
    k_transpose_w<64, 64, 1><<<(4096 + 255) / 256, 256, 0, stream>>>(w_sk2, wsk2);
    k_transpose_w<32, 32, 1><<<(1024 + 255) / 256, 256, 0, stream>>>(w_sk1, wsk1);
    k_eff<64, 128><<<(2 * 64 * 128 + 255) / 256, 256, 0, stream>>>(w_d3, eff3);
    k_eff<32, 64><<<(2 * 32 * 64 + 255) / 256, 256, 0, stream>>>(w_d2, eff2);
    k_eff<32, 32><<<(2 * 32 * 32 + 255) / 256, 256, 0, stream>>>(w_d1, eff1);

    for (int t = 0; t < TSTEPS; ++t) {
        float inv = 1.0f / (float)(t + 1);
        // e1: 32oc in 2 chunks -> 1024 blocks
        k_e1<16><<<dim3(8, 8, NB * 2), 256, 0, stream>>>(x, wTe1, b_e1, me1, mn1, s1, t, inv);
        // e2: 64oc in 8 chunks -> 1024 blocks
        k_enc<32, 64, 64, 8, true><<<dim3(4, 4, NB * 8), 256, 0, stream>>>(
            s1, wTe2, b_e2, me2, mn2, s2, inv);
        // e3: 128oc in 32 chunks -> 1024 blocks
        k_enc<64, 128, 32, 4, false><<<dim3(2, 2, NB * 32), 256, 0, stream>>>(
            s2, wTe3, b_e3, me3, (float*)nullptr, s3, 0.f);
        // d3: 64oc in 16 chunks, ICCH=64 (19.6KB LDS) -> 1024 blocks
        k_dec<128, 64, 32, 4, 64, true, true, false><<<dim3(2, 2, NB * 2 * 16), 256, 0, stream>>>(
            s3, eff3, b_d3, md3, mn2, wsk2, d3f, 1);
        // d2: 32oc in 4 chunks, ICCH=16 (19.6KB LDS) -> 1024 blocks
        k_dec<64, 32, 64, 8, 16, true, false, false><<<dim3(4, 4, NB * 2 * 4), 256, 0, stream>>>(
            d3f, eff2, b_d2, md2, mn1, wsk1, d2f, 1);
        // d1: 32oc in 4 chunks, ICCH=16 -> 4096 blocks
        k_dec<32, 32, 128, 8, 16, false, false, true><<<dim3(8, 8, NB * 2 * 4), 256, 0, stream>>>(
            d2f, eff1, b_d1, md1, (const float*)nullptr, (const float*)nullptr, d1u,
            (t == TSTEPS - 1) ? 1 : 0);
    }
    k_flow<<<dim3(16, 16, NB), 256, 0, stream>>>(d1u, wTfl, b_fl, (float*)d_out);
}

// Round 9
// 5926.875 us; speedup vs baseline: 1.0279x; 1.0180x over previous
//
#include <hip/hip_runtime.h>

// =====================  problem constants  =====================
constexpr int NB = 8;        // batch
constexpr int TSTEPS = 10;   // timesteps

// =====================  workspace layout (bytes)  =====================
constexpr size_t SZ_ME1 = (size_t)NB*32*128*128*4;
constexpr size_t SZ_ME2 = (size_t)NB*64*64*64*4;
constexpr size_t SZ_ME3 = (size_t)NB*128*32*32*4;
constexpr size_t SZ_MD3 = SZ_ME2;
constexpr size_t SZ_MD2 = SZ_ME1;
constexpr size_t SZ_MD1 = (size_t)NB*32*256*256*4;
constexpr size_t SZ_MN1 = SZ_ME1;
constexpr size_t SZ_MN2 = SZ_ME2;

constexpr size_t O_ME1 = 0;
constexpr size_t O_ME2 = O_ME1 + SZ_ME1;
constexpr size_t O_ME3 = O_ME2 + SZ_ME2;
constexpr size_t O_MD3 = O_ME3 + SZ_ME3;
constexpr size_t O_MD2 = O_MD3 + SZ_MD3;
constexpr size_t O_MD1 = O_MD2 + SZ_MD2;
constexpr size_t O_MN1 = O_MD1 + SZ_MD1;
constexpr size_t O_MN2 = O_MN1 + SZ_MN1;
constexpr size_t ZERO_BYTES = O_MN2 + SZ_MN2;   // 146,800,640 B zeroed each launch

constexpr size_t O_S1  = ZERO_BYTES;                       // u8 spikes
constexpr size_t O_S2  = O_S1  + (size_t)NB*32*128*128;
constexpr size_t O_S3  = O_S2  + (size_t)NB*64*64*64;
constexpr size_t O_D3F = O_S3  + (size_t)NB*128*32*32;     // float (spike+skip)
constexpr size_t O_D2F = O_D3F + SZ_MD3;
constexpr size_t O_D1U = O_D2F + SZ_MD2;                   // u8 spikes
constexpr size_t O_EFF3 = O_D1U + (size_t)NB*32*256*256;   // eff tables (float)
constexpr size_t O_EFF2 = O_EFF3 + (size_t)2*64*128*8*4;
constexpr size_t O_EFF1 = O_EFF2 + (size_t)2*32*64*8*4;
constexpr size_t O_WTE1 = O_EFF1 + (size_t)2*32*32*8*4;    // transposed weights
constexpr size_t O_WTE2 = O_WTE1 + (size_t)2*5*5*32*4;
constexpr size_t O_WTE3 = O_WTE2 + (size_t)32*3*3*64*4;
constexpr size_t O_WTFL = O_WTE3 + (size_t)64*3*3*128*4;
constexpr size_t O_WSK2 = O_WTFL + (size_t)32*3*3*2*4;
constexpr size_t O_WSK1 = O_WSK2 + (size_t)64*64*4;
// end: ~188 MiB

// =====================  prepass kernels  =====================
// wT[((ci*K+ky)*K+kx)*OC + oc] = w[((oc*IC+ci)*K+ky)*K+kx]
template<int OC, int IC, int K>
__global__ void k_transpose_w(const float* __restrict__ w, float* __restrict__ wT) {
    int i = blockIdx.x * 256 + threadIdx.x;
    constexpr int total = OC * IC * K * K;
    if (i >= total) return;
    int oc = i % OC; int r = i / OC;
    int kx = r % K;  r /= K;
    int ky = r % K;  r /= K;
    int ci = r;
    wT[i] = w[((oc * IC + ci) * K + ky) * K + kx];
}

// eff[((py*OC+oc)*IC+ci)*8 + (px*4 + di*2 + dj)]
// upsample2-then-conv3x3 collapsed to 2x2 conv per output parity
template<int OC, int IC>
__global__ void k_eff(const float* __restrict__ w, float* __restrict__ eff) {
    int i = blockIdx.x * 256 + threadIdx.x;
    constexpr int total = 2 * OC * IC;
    if (i >= total) return;
    int ci = i % IC; int r = i / IC;
    int oc = r % OC; int py = r / OC;
    const float* wp = w + ((size_t)oc * IC + ci) * 9;
    float w00=wp[0],w01=wp[1],w02=wp[2],w10=wp[3],w11=wp[4],w12=wp[5],w20=wp[6],w21=wp[7],w22=wp[8];
    float r0c0,r0c1,r0c2,r1c0,r1c1,r1c2;
    if (py == 0) { r0c0=w00;     r0c1=w01;     r0c2=w02;     r1c0=w10+w20; r1c1=w11+w21; r1c2=w12+w22; }
    else         { r0c0=w00+w10; r0c1=w01+w11; r0c2=w02+w12; r1c0=w20;     r1c1=w21;     r1c2=w22;     }
    float* e = eff + (size_t)i * 8;
    e[0] = r0c0;        e[1] = r0c1 + r0c2;   // px=0
    e[2] = r1c0;        e[3] = r1c1 + r1c2;
    e[4] = r0c0 + r0c1; e[5] = r0c2;          // px=1
    e[6] = r1c0 + r1c1; e[7] = r1c2;
}

// =====================  encoder layer 1 (5x5 s2 p2, fp32 input)  =====================
template<int OCCH>
__global__ __launch_bounds__(256) void k_e1(
    const float* __restrict__ x, const float* __restrict__ wT, const float* __restrict__ b,
    float* __restrict__ me1, float* __restrict__ mn1, unsigned char* __restrict__ s1,
    int t, float inv)
{
    __shared__ float tile[2 * 35 * 36];
    const int tx = threadIdx.x & 15, ty = threadIdx.x >> 4;
    constexpr int nchunks = 32 / OCCH;
    int zi = blockIdx.z;
    const int ocb = (zi % nchunks) * OCCH;
    const int n = zi / nchunks;
    const int oy0 = blockIdx.y * 16, ox0 = blockIdx.x * 16;
    const int iy0 = oy0 * 2 - 2, ix0 = ox0 * 2 - 2;

    for (int e = threadIdx.x; e < 2 * 35 * 35; e += 256) {
        int c = e % 35; int r = (e / 35) % 35; int ci = e / (35 * 35);
        int gy = iy0 + r, gx = ix0 + c;
        float v = 0.f;
        if (gy >= 0 && gy < 256 && gx >= 0 && gx < 256)
            v = x[((((size_t)n * TSTEPS + t) * 2 + ci) * 256 + gy) * 256 + gx];
        tile[(ci * 35 + r) * 36 + c] = v;
    }
    __syncthreads();

    float acc[OCCH];
#pragma unroll
    for (int oc = 0; oc < OCCH; ++oc) acc[oc] = b[ocb + oc];
#pragma unroll
    for (int ci = 0; ci < 2; ++ci)
#pragma unroll
        for (int ky = 0; ky < 5; ++ky)
#pragma unroll
            for (int kx = 0; kx < 5; ++kx) {
                float v = tile[(ci * 35 + ty * 2 + ky) * 36 + tx * 2 + kx];
                const float* wp = wT + ((ci * 5 + ky) * 5 + kx) * 32 + ocb;
#pragma unroll
                for (int oc = 0; oc < OCCH; ++oc) acc[oc] = fmaf(v, wp[oc], acc[oc]);
            }

    const int oy = oy0 + ty, ox = ox0 + tx;
#pragma unroll
    for (int oc = 0; oc < OCCH; ++oc) {
        size_t idx = (((size_t)n * 32 + ocb + oc) * 128 + oy) * 128 + ox;
        float mo = me1[idx];
        float m  = mo + (acc[oc] - mo) * 0.5f;
        float s  = (m > 1.0f) ? 1.0f : 0.0f;
        me1[idx] = m - s;
        float mn = mn1[idx];
        mn1[idx] = mn + (s - mn) * inv;
        s1[idx]  = (unsigned char)s;
    }
}

// =====================  encoder stride-2 3x3 conv + LIF (e2/e3)  =====================
// Staging uses a fixed 7-row x 34-col thread map (no div/mod in the loop).
template<int IC, int OC, int OUT, int OCCH, bool MEAN>
__global__ __launch_bounds__(256) void k_enc(
    const unsigned char* __restrict__ sin, const float* __restrict__ wT, const float* __restrict__ b,
    float* __restrict__ mem, float* __restrict__ mn, unsigned char* __restrict__ sout, float inv)
{
    constexpr int IN = OUT * 2;
    constexpr int ICCH = 32;
    constexpr int TH = 33, TW = 34;
    __shared__ unsigned char tile[ICCH * TH * TW];
    const int tx = threadIdx.x & 15, ty = threadIdx.x >> 4;
    const int nchunks = OC / OCCH;
    const int zi = blockIdx.z;
    const int n   = zi / nchunks;
    const int ocb = (zi % nchunks) * OCCH;
    const int oy0 = blockIdx.y * 16, ox0 = blockIdx.x * 16;
    const int iy0 = oy0 * 2 - 1, ix0 = ox0 * 2 - 1;

    // staging map: 238 active threads = 7 rows x 34 cols; rows advance by 7
    const int sc = (int)threadIdx.x % 34;
    const int sr = (int)threadIdx.x / 34;
    const int sgx = ix0 + sc;
    const bool sactive = threadIdx.x < 238;
    const bool colok = sactive && (sgx >= 0) && (sgx < IN);

    float acc[OCCH];
#pragma unroll
    for (int oc = 0; oc < OCCH; ++oc) acc[oc] = b[ocb + oc];

    for (int icc = 0; icc < IC; icc += ICCH) {
        __syncthreads();
        for (int ci = 0; ci < ICCH; ++ci) {
            const unsigned char* srcp = sin + ((size_t)n * IC + icc + ci) * IN * IN;
#pragma unroll
            for (int s = 0; s < 5; ++s) {
                int row = sr + 7 * s;
                if (row < TH) {
                    int gy = iy0 + row;
                    unsigned char v = 0;
                    if (colok && gy >= 0 && gy < IN) v = srcp[(size_t)gy * IN + sgx];
                    if (sactive) tile[(ci * TH + row) * TW + sc] = v;
                }
            }
        }
        __syncthreads();
#pragma unroll 2
        for (int ci = 0; ci < ICCH; ++ci) {
#pragma unroll
            for (int ky = 0; ky < 3; ++ky)
#pragma unroll
                for (int kx = 0; kx < 3; ++kx) {
                    float v = (float)tile[(ci * TH + ty * 2 + ky) * TW + tx * 2 + kx];
                    const float* wp = wT + (((icc + ci) * 3 + ky) * 3 + kx) * OC + ocb;
#pragma unroll
                    for (int oc = 0; oc < OCCH; ++oc) acc[oc] = fmaf(v, wp[oc], acc[oc]);
                }
        }
    }

    const int oy = oy0 + ty, ox = ox0 + tx;
#pragma unroll
    for (int oc = 0; oc < OCCH; ++oc) {
        size_t idx = (((size_t)n * OC + ocb + oc) * OUT + oy) * OUT + ox;
        float mo = mem[idx];
        float m  = mo + (acc[oc] - mo) * 0.5f;
        float s  = (m > 1.0f) ? 1.0f : 0.0f;
        mem[idx] = m - s;
        if constexpr (MEAN) { float mv = mn[idx]; mn[idx] = mv + (s - mv) * inv; }
        sout[idx] = (unsigned char)s;
    }
}

// =====================  decoder: upsample2 + conv3x3 + LIF (+1x1 skip)  =====================
// Parity decomposition: block handles one row-parity plane; each thread computes the
// (even,odd) column pair -> float2-coalesced membrane/output access, wave-uniform eff weights.
// store_out==0 skips the spike store (d1 for t<9: spikes feed only the final flow conv).
template<int IC, int OC, int SRC, int OCCH, int ICCH, bool SKIP, bool SRCU8, bool OUTU8>
__global__ __launch_bounds__(256) void k_dec(
    const void* __restrict__ srcv, const float* __restrict__ eff, const float* __restrict__ b,
    float* __restrict__ mem, const float* __restrict__ mnsk, const float* __restrict__ wskT,
    void* __restrict__ outv, int store_out)
{
    constexpr int OUT = SRC * 2;
    constexpr int TH = 17, TW = 18;
    __shared__ __align__(16) unsigned char smem[ICCH * TH * TW * (SRCU8 ? 1 : 4)];
    unsigned char* tileB = smem;
    float* tileF = (float*)smem;
    const unsigned char* src8 = (const unsigned char*)srcv;
    const float* srcF = (const float*)srcv;

    const int tx = threadIdx.x & 15, ty = threadIdx.x >> 4;
    constexpr int nchunks = OC / OCCH;
    int zi = blockIdx.z;
    const int ocb = (zi % nchunks) * OCCH; zi /= nchunks;
    const int py = zi & 1;
    const int n  = zi >> 1;
    const int i0 = blockIdx.y * 16;   // plane-row base
    const int j0 = blockIdx.x * 16;   // plane-col base (each thread col = 2 out cols)
    const int rbase0 = i0 - 1 + py;
    const int cbase0 = j0 - 1;

    float accA[OCCH], accB[OCCH];
#pragma unroll
    for (int oc = 0; oc < OCCH; ++oc) { accA[oc] = 0.f; accB[oc] = 0.f; }

    for (int icc = 0; icc < IC; icc += ICCH) {
        __syncthreads();
        for (int e = threadIdx.x; e < ICCH * TH * TW; e += 256) {
            int c = e % TW; int r = (e / TW) % TH; int ci = e / (TH * TW);
            int gy = rbase0 + r, gx = cbase0 + c;
            bool ok = (gy >= 0 && gy < SRC && gx >= 0 && gx < SRC);
            size_t gidx = (((size_t)n * IC + icc + ci) * SRC + gy) * SRC + gx;
            if constexpr (SRCU8) tileB[e] = ok ? src8[gidx] : (unsigned char)0;
            else                 tileF[e] = ok ? srcF[gidx] : 0.f;
        }
        __syncthreads();
#pragma unroll 2
        for (int ci = 0; ci < ICCH; ++ci) {
            float s00, s01, s02, s10, s11, s12;
            const int base = (ci * TH + ty) * TW + tx;
            if constexpr (SRCU8) {
                s00 = (float)tileB[base];      s01 = (float)tileB[base + 1];      s02 = (float)tileB[base + 2];
                s10 = (float)tileB[base + TW]; s11 = (float)tileB[base + TW + 1]; s12 = (float)tileB[base + TW + 2];
            } else {
                s00 = tileF[base];      s01 = tileF[base + 1];      s02 = tileF[base + 2];
                s10 = tileF[base + TW]; s11 = tileF[base + TW + 1]; s12 = tileF[base + TW + 2];
            }
#pragma unroll
            for (int oc = 0; oc < OCCH; ++oc) {
                const float* e8 = eff + ((((size_t)py * OC + ocb + oc) * IC) + icc + ci) * 8;
                accA[oc] = fmaf(s00, e8[0], accA[oc]);
                accA[oc] = fmaf(s01, e8[1], accA[oc]);
                accA[oc] = fmaf(s10, e8[2], accA[oc]);
                accA[oc] = fmaf(s11, e8[3], accA[oc]);
                accB[oc] = fmaf(s01, e8[4], accB[oc]);
                accB[oc] = fmaf(s02, e8[5], accB[oc]);
                accB[oc] = fmaf(s11, e8[6], accB[oc]);
                accB[oc] = fmaf(s12, e8[7], accB[oc]);
            }
        }
    }

    const int oy  = 2 * (i0 + ty) + py;
    const int ox0 = 2 * (j0 + tx);

    // LIF (soft reset); spike values left in accA/accB
#pragma unroll
    for (int oc = 0; oc < OCCH; ++oc) {
        int ocg = ocb + oc;
        size_t idx = (((size_t)n * OC + ocg) * OUT + oy) * OUT + ox0;
        float2 mv = *(const float2*)(mem + idx);
        float bb = b[ocg];
        float cA = accA[oc] + bb, cB = accB[oc] + bb;
        float mA = mv.x + (cA - mv.x) * 0.5f;
        float mB = mv.y + (cB - mv.y) * 0.5f;
        float sA = (mA > 1.f) ? 1.f : 0.f;
        float sB = (mB > 1.f) ? 1.f : 0.f;
        *(float2*)(mem + idx) = make_float2(mA - sA, mB - sB);
        accA[oc] = sA; accB[oc] = sB;
    }

    if constexpr (SKIP) {   // 1x1 conv over running mean, added AFTER spike
#pragma unroll 4
        for (int ci = 0; ci < OC; ++ci) {
            size_t sidx = (((size_t)n * OC + ci) * OUT + oy) * OUT + ox0;
            float2 v = *(const float2*)(mnsk + sidx);
            const float* wp = wskT + ci * OC + ocb;
#pragma unroll
            for (int oc = 0; oc < OCCH; ++oc) {
                accA[oc] = fmaf(v.x, wp[oc], accA[oc]);
                accB[oc] = fmaf(v.y, wp[oc], accB[oc]);
            }
        }
    }

    if (store_out) {
#pragma unroll
        for (int oc = 0; oc < OCCH; ++oc) {
            int ocg = ocb + oc;
            size_t idx = (((size_t)n * OC + ocg) * OUT + oy) * OUT + ox0;
            if constexpr (OUTU8) {
                unsigned char* o8 = (unsigned char*)outv;
                o8[idx]     = (unsigned char)accA[oc];
                o8[idx + 1] = (unsigned char)accB[oc];
            } else {
                *(float2*)((float*)outv + idx) = make_float2(accA[oc], accB[oc]);
            }
        }
    }
}

// =====================  final flow conv (3x3 s1 p1, 32->2, *16)  =====================
__global__ __launch_bounds__(256) void k_flow(
    const unsigned char* __restrict__ d1, const float* __restrict__ wT, const float* __restrict__ b,
    float* __restrict__ out)
{
    constexpr int HW = 256;
    __shared__ unsigned char tile[32 * 18 * 19];
    const int tx = threadIdx.x & 15, ty = threadIdx.x >> 4;
    const int n = blockIdx.z;
    const int oy0 = blockIdx.y * 16, ox0 = blockIdx.x * 16;

    for (int e = threadIdx.x; e < 32 * 18 * 18; e += 256) {
        int c = e % 18; int r = (e / 18) % 18; int ci = e / (18 * 18);
        int gy = oy0 - 1 + r, gx = ox0 - 1 + c;
        unsigned char v = 0;
        if (gy >= 0 && gy < HW && gx >= 0 && gx < HW)
            v = d1[(((size_t)n * 32 + ci) * HW + gy) * HW + gx];
        tile[(ci * 18 + r) * 19 + c] = v;
    }
    __syncthreads();

    float a0 = b[0], a1 = b[1];
#pragma unroll 2
    for (int ci = 0; ci < 32; ++ci)
#pragma unroll
        for (int ky = 0; ky < 3; ++ky)
#pragma unroll
            for (int kx = 0; kx < 3; ++kx) {
                float v = (float)tile[(ci * 18 + ty + ky) * 19 + tx + kx];
                const float* wp = wT + ((ci * 3 + ky) * 3 + kx) * 2;
                a0 = fmaf(v, wp[0], a0);
                a1 = fmaf(v, wp[1], a1);
            }

    const int oy = oy0 + ty, ox = ox0 + tx;
    out[(((size_t)n * 2 + 0) * HW + oy) * HW + ox] = a0 * 16.f;
    out[(((size_t)n * 2 + 1) * HW + oy) * HW + ox] = a1 * 16.f;
}

// =====================  launch  =====================
extern "C" void kernel_launch(void* const* d_in, const int* in_sizes, int n_in,
                              void* d_out, int out_size, void* d_ws, size_t ws_size,
                              hipStream_t stream)
{
    const float* x     = (const float*)d_in[0];
    const float* w_e1  = (const float*)d_in[1];
    const float* b_e1  = (const float*)d_in[2];
    const float* w_e2  = (const float*)d_in[3];
    const float* b_e2  = (const float*)d_in[4];
    const float* w_e3  = (const float*)d_in[5];
    const float* b_e3  = (const float*)d_in[6];
    const float* w_d3  = (const float*)d_in[7];
    const float* b_d3  = (const float*)d_in[8];
    const float* w_d2  = (const float*)d_in[9];
    const float* b_d2  = (const float*)d_in[10];
    const float* w_d1  = (const float*)d_in[11];
    const float* b_d1  = (const float*)d_in[12];
    const float* w_sk2 = (const float*)d_in[13];
    const float* w_sk1 = (const float*)d_in[14];
    const float* w_fl  = (const float*)d_in[15];
    const float* b_fl  = (const float*)d_in[16];

    char* ws = (char*)d_ws;
    float* me1 = (float*)(ws + O_ME1);
    float* me2 = (float*)(ws + O_ME2);
    float* me3 = (float*)(ws + O_ME3);
    float* md3 = (float*)(ws + O_MD3);
    float* md2 = (float*)(ws + O_MD2);
    float* md1 = (float*)(ws + O_MD1);
    float* mn1 = (float*)(ws + O_MN1);
    float* mn2 = (float*)(ws + O_MN2);
    unsigned char* s1  = (unsigned char*)(ws + O_S1);
    unsigned char* s2  = (unsigned char*)(ws + O_S2);
    unsigned char* s3  = (unsigned char*)(ws + O_S3);
    float* d3f = (float*)(ws + O_D3F);
    float* d2f = (float*)(ws + O_D2F);
    unsigned char* d1u = (unsigned char*)(ws + O_D1U);
    float* eff3 = (float*)(ws + O_EFF3);
    float* eff2 = (float*)(ws + O_EFF2);
    float* eff1 = (float*)(ws + O_EFF1);
    float* wTe1 = (float*)(ws + O_WTE1);
    float* wTe2 = (float*)(ws + O_WTE2);
    float* wTe3 = (float*)(ws + O_WTE3);
    float* wTfl = (float*)(ws + O_WTFL);
    float* wsk2 = (float*)(ws + O_WSK2);
    float* wsk1 = (float*)(ws + O_WSK1);

    // zero all membrane / running-mean state (ws is poisoned before every call)
    hipMemsetAsync(d_ws, 0, ZERO_BYTES, stream);

    // prepass: weight transposes + effective upsample-conv weight tables
    k_transpose_w<32, 2, 5><<<(1600 + 255) / 256, 256, 0, stream>>>(w_e1, wTe1);
    k_transpose_w<64, 32, 3><<<(18432 + 255) / 256, 256, 0, stream>>>(w_e2, wTe2);
    k_transpose_w<128, 64, 3><<<(73728 + 255) / 256, 256, 0, stream>>>(w_e3, wTe3);
    k_transpose_w<2, 32, 3><<<(576 + 255) / 256, 256, 0, stream>>>(w_fl, wTfl);
    k_transpose_w<64, 64, 1><<<(4096 + 255) / 256, 256, 0, stream>>>(w_sk2, wsk2);
    k_transpose_w<32, 32, 1><<<(1024 + 255) / 256, 256, 0, stream>>>(w_sk1, wsk1);
    k_eff<64, 128><<<(2 * 64 * 128 + 255) / 256, 256, 0, stream>>>(w_d3, eff3);
    k_eff<32, 64><<<(2 * 32 * 64 + 255) / 256, 256, 0, stream>>>(w_d2, eff2);
    k_eff<32, 32><<<(2 * 32 * 32 + 255) / 256, 256, 0, stream>>>(w_d1, eff1);

    for (int t = 0; t < TSTEPS; ++t) {
        float inv = 1.0f / (float)(t + 1);
        // e1: 32oc in 2 chunks -> 1024 blocks
        k_e1<16><<<dim3(8, 8, NB * 2), 256, 0, stream>>>(x, wTe1, b_e1, me1, mn1, s1, t, inv);
        // e2: 64oc in 8 chunks -> 1024 blocks
        k_enc<32, 64, 64, 8, true><<<dim3(4, 4, NB * 8), 256, 0, stream>>>(
            s1, wTe2, b_e2, me2, mn2, s2, inv);
        // e3: 128oc in 32 chunks -> 1024 blocks
        k_enc<64, 128, 32, 4, false><<<dim3(2, 2, NB * 32), 256, 0, stream>>>(
            s2, wTe3, b_e3, me3, (float*)nullptr, s3, 0.f);
        // d3: 64oc in 16 chunks, ICCH=64 (19.6KB LDS) -> 1024 blocks
        k_dec<128, 64, 32, 4, 64, true, true, false><<<dim3(2, 2, NB * 2 * 16), 256, 0, stream>>>(
            s3, eff3, b_d3, md3, mn2, wsk2, d3f, 1);
        // d2: 32oc in 4 chunks, ICCH=16 (19.6KB LDS) -> 1024 blocks
        k_dec<64, 32, 64, 8, 16, true, false, false><<<dim3(4, 4, NB * 2 * 4), 256, 0, stream>>>(
            d3f, eff2, b_d2, md2, mn1, wsk1, d2f, 1);
        // d1: 32oc in 4 chunks, ICCH=16 -> 4096 blocks
        k_dec<32, 32, 128, 8, 16, false, false, true><<<dim3(8, 8, NB * 2 * 4), 256, 0, stream>>>(
            d2f, eff1, b_d1, md1, (const float*)nullptr, (const float*)nullptr, d1u,
            (t == TSTEPS - 1) ? 1 : 0);
    }
    k_flow<<<dim3(16, 16, NB), 256, 0, stream>>>(d1u, wTfl, b_fl, (float*)d_out);
}

// Round 10
// 4662.850 us; speedup vs baseline: 1.3065x; 1.2711x over previous
//
#include <hip/hip_runtime.h>

// =====================  problem constants  =====================
constexpr int NB = 8;        // batch
constexpr int TSTEPS = 10;   // timesteps

// =====================  workspace layout (bytes)  =====================
constexpr size_t SZ_ME1 = (size_t)NB*32*128*128*4;
constexpr size_t SZ_ME2 = (size_t)NB*64*64*64*4;
constexpr size_t SZ_ME3 = (size_t)NB*128*32*32*4;
constexpr size_t SZ_MD3 = SZ_ME2;
constexpr size_t SZ_MD2 = SZ_ME1;
constexpr size_t SZ_MD1 = (size_t)NB*32*256*256*4;
constexpr size_t SZ_MN1 = SZ_ME1;
constexpr size_t SZ_MN2 = SZ_ME2;
constexpr size_t SZ_S3P = (size_t)NB*128*34*36;   // zero-padded e3 spikes (u8)

constexpr size_t O_ME1 = 0;
constexpr size_t O_ME2 = O_ME1 + SZ_ME1;
constexpr size_t O_ME3 = O_ME2 + SZ_ME2;
constexpr size_t O_MD3 = O_ME3 + SZ_ME3;
constexpr size_t O_MD2 = O_MD3 + SZ_MD3;
constexpr size_t O_MD1 = O_MD2 + SZ_MD2;
constexpr size_t O_MN1 = O_MD1 + SZ_MD1;
constexpr size_t O_MN2 = O_MN1 + SZ_MN1;
constexpr size_t O_S3P = O_MN2 + SZ_MN2;
constexpr size_t ZERO_BYTES = O_S3P + SZ_S3P;   // ~148 MB zeroed each launch (pad stays 0)

constexpr size_t O_S1  = ZERO_BYTES;                       // u8 spikes (e1 out)
constexpr size_t O_S2  = O_S1  + (size_t)NB*32*128*128;    // u8 spikes (e2 out)
constexpr size_t O_D3F = O_S2  + (size_t)NB*64*64*64;      // float (d3 spike+skip)
constexpr size_t O_D2F = O_D3F + SZ_MD3;
constexpr size_t O_D1U = O_D2F + SZ_MD2;                   // u8 spikes (d1 out)
constexpr size_t O_EFF3 = O_D1U + (size_t)NB*32*256*256;   // eff tables (float)
constexpr size_t O_EFF2 = O_EFF3 + (size_t)2*64*128*8*4;
constexpr size_t O_EFF1 = O_EFF2 + (size_t)2*32*64*8*4;
constexpr size_t O_WTE1 = O_EFF1 + (size_t)2*32*32*8*4;    // transposed weights
constexpr size_t O_WTE2 = O_WTE1 + (size_t)2*5*5*32*4;
constexpr size_t O_WTE3 = O_WTE2 + (size_t)32*3*3*64*4;
constexpr size_t O_WTFL = O_WTE3 + (size_t)64*3*3*128*4;
constexpr size_t O_WSK2 = O_WTFL + (size_t)32*3*3*2*4;
constexpr size_t O_WSK1 = O_WSK2 + (size_t)64*64*4;
// end: ~189 MiB

// =====================  prepass kernels  =====================
template<int OC, int IC, int K>
__global__ void k_transpose_w(const float* __restrict__ w, float* __restrict__ wT) {
    int i = blockIdx.x * 256 + threadIdx.x;
    constexpr int total = OC * IC * K * K;
    if (i >= total) return;
    int oc = i % OC; int r = i / OC;
    int kx = r % K;  r /= K;
    int ky = r % K;  r /= K;
    int ci = r;
    wT[i] = w[((oc * IC + ci) * K + ky) * K + kx];
}

// eff[((py*OC+oc)*IC+ci)*8 + (px*4 + di*2 + dj)]
template<int OC, int IC>
__global__ void k_eff(const float* __restrict__ w, float* __restrict__ eff) {
    int i = blockIdx.x * 256 + threadIdx.x;
    constexpr int total = 2 * OC * IC;
    if (i >= total) return;
    int ci = i % IC; int r = i / IC;
    int oc = r % OC; int py = r / OC;
    const float* wp = w + ((size_t)oc * IC + ci) * 9;
    float w00=wp[0],w01=wp[1],w02=wp[2],w10=wp[3],w11=wp[4],w12=wp[5],w20=wp[6],w21=wp[7],w22=wp[8];
    float r0c0,r0c1,r0c2,r1c0,r1c1,r1c2;
    if (py == 0) { r0c0=w00;     r0c1=w01;     r0c2=w02;     r1c0=w10+w20; r1c1=w11+w21; r1c2=w12+w22; }
    else         { r0c0=w00+w10; r0c1=w01+w11; r0c2=w02+w12; r1c0=w20;     r1c1=w21;     r1c2=w22;     }
    float* e = eff + (size_t)i * 8;
    e[0] = r0c0;        e[1] = r0c1 + r0c2;   // px=0
    e[2] = r1c0;        e[3] = r1c1 + r1c2;
    e[4] = r0c0 + r0c1; e[5] = r0c2;          // px=1
    e[6] = r1c0 + r1c1; e[7] = r1c2;
}

// =====================  encoder layer 1 (5x5 s2 p2, fp32 input)  =====================
template<int OCCH>
__global__ __launch_bounds__(256) void k_e1(
    const float* __restrict__ x, const float* __restrict__ wT, const float* __restrict__ b,
    float* __restrict__ me1, float* __restrict__ mn1, unsigned char* __restrict__ s1,
    int t, float inv)
{
    __shared__ float tile[2 * 35 * 36];
    const int tx = threadIdx.x & 15, ty = threadIdx.x >> 4;
    constexpr int nchunks = 32 / OCCH;
    int zi = blockIdx.z;
    const int ocb = (zi % nchunks) * OCCH;
    const int n = zi / nchunks;
    const int oy0 = blockIdx.y * 16, ox0 = blockIdx.x * 16;
    const int iy0 = oy0 * 2 - 2, ix0 = ox0 * 2 - 2;

    for (int e = threadIdx.x; e < 2 * 35 * 35; e += 256) {
        int c = e % 35; int r = (e / 35) % 35; int ci = e / (35 * 35);
        int gy = iy0 + r, gx = ix0 + c;
        float v = 0.f;
        if (gy >= 0 && gy < 256 && gx >= 0 && gx < 256)
            v = x[((((size_t)n * TSTEPS + t) * 2 + ci) * 256 + gy) * 256 + gx];
        tile[(ci * 35 + r) * 36 + c] = v;
    }
    __syncthreads();

    float acc[OCCH];
#pragma unroll
    for (int oc = 0; oc < OCCH; ++oc) acc[oc] = b[ocb + oc];
#pragma unroll
    for (int ci = 0; ci < 2; ++ci)
#pragma unroll
        for (int ky = 0; ky < 5; ++ky)
#pragma unroll
            for (int kx = 0; kx < 5; ++kx) {
                float v = tile[(ci * 35 + ty * 2 + ky) * 36 + tx * 2 + kx];
                const float* wp = wT + ((ci * 5 + ky) * 5 + kx) * 32 + ocb;
#pragma unroll
                for (int oc = 0; oc < OCCH; ++oc) acc[oc] = fmaf(v, wp[oc], acc[oc]);
            }

    const int oy = oy0 + ty, ox = ox0 + tx;
#pragma unroll
    for (int oc = 0; oc < OCCH; ++oc) {
        size_t idx = (((size_t)n * 32 + ocb + oc) * 128 + oy) * 128 + ox;
        float mo = me1[idx];
        float m  = mo + (acc[oc] - mo) * 0.5f;
        float s  = (m > 1.0f) ? 1.0f : 0.0f;
        me1[idx] = m - s;
        float mn = mn1[idx];
        mn1[idx] = mn + (s - mn) * inv;
        s1[idx]  = (unsigned char)s;
    }
}

// =====================  encoder stride-2 3x3 conv + LIF (e2/e3)  =====================
// PADOUT: store spikes into zero-padded [34][36] planes (d3 direct-global reader).
template<int IC, int OC, int OUT, int OCCH, bool MEAN, bool PADOUT>
__global__ __launch_bounds__(256) void k_enc(
    const unsigned char* __restrict__ sin, const float* __restrict__ wT, const float* __restrict__ b,
    float* __restrict__ mem, float* __restrict__ mn, unsigned char* __restrict__ sout, float inv)
{
    constexpr int IN = OUT * 2;
    constexpr int ICCH = 32;
    constexpr int TH = 33, TW = 34;
    __shared__ unsigned char tile[ICCH * TH * TW];
    const int tx = threadIdx.x & 15, ty = threadIdx.x >> 4;
    const int nchunks = OC / OCCH;
    const int zi = blockIdx.z;
    const int n   = zi / nchunks;
    const int ocb = (zi % nchunks) * OCCH;
    const int oy0 = blockIdx.y * 16, ox0 = blockIdx.x * 16;
    const int iy0 = oy0 * 2 - 1, ix0 = ox0 * 2 - 1;

    const int sc = (int)threadIdx.x % 34;
    const int sr = (int)threadIdx.x / 34;
    const int sgx = ix0 + sc;
    const bool sactive = threadIdx.x < 238;
    const bool colok = sactive && (sgx >= 0) && (sgx < IN);

    float acc[OCCH];
#pragma unroll
    for (int oc = 0; oc < OCCH; ++oc) acc[oc] = b[ocb + oc];

    for (int icc = 0; icc < IC; icc += ICCH) {
        __syncthreads();
        for (int ci = 0; ci < ICCH; ++ci) {
            const unsigned char* srcp = sin + ((size_t)n * IC + icc + ci) * IN * IN;
#pragma unroll
            for (int s = 0; s < 5; ++s) {
                int row = sr + 7 * s;
                if (row < TH) {
                    int gy = iy0 + row;
                    unsigned char v = 0;
                    if (colok && gy >= 0 && gy < IN) v = srcp[(size_t)gy * IN + sgx];
                    if (sactive) tile[(ci * TH + row) * TW + sc] = v;
                }
            }
        }
        __syncthreads();
#pragma unroll 2
        for (int ci = 0; ci < ICCH; ++ci) {
#pragma unroll
            for (int ky = 0; ky < 3; ++ky)
#pragma unroll
                for (int kx = 0; kx < 3; ++kx) {
                    float v = (float)tile[(ci * TH + ty * 2 + ky) * TW + tx * 2 + kx];
                    const float* wp = wT + (((icc + ci) * 3 + ky) * 3 + kx) * OC + ocb;
#pragma unroll
                    for (int oc = 0; oc < OCCH; ++oc) acc[oc] = fmaf(v, wp[oc], acc[oc]);
                }
        }
    }

    const int oy = oy0 + ty, ox = ox0 + tx;
#pragma unroll
    for (int oc = 0; oc < OCCH; ++oc) {
        size_t idx = (((size_t)n * OC + ocb + oc) * OUT + oy) * OUT + ox;
        float mo = mem[idx];
        float m  = mo + (acc[oc] - mo) * 0.5f;
        float s  = (m > 1.0f) ? 1.0f : 0.0f;
        mem[idx] = m - s;
        if constexpr (MEAN) { float mv = mn[idx]; mn[idx] = mv + (s - mv) * inv; }
        if constexpr (PADOUT)
            sout[((size_t)(n * OC + ocb + oc) * 34 + 1 + oy) * 36 + 1 + ox] = (unsigned char)s;
        else
            sout[idx] = (unsigned char)s;
    }
}

// =====================  d3 decoder: direct-global, no LDS, no barriers  =====================
__global__ __launch_bounds__(256) void k_dec3(
    const unsigned char* __restrict__ s3p, const float* __restrict__ eff,
    const float* __restrict__ b, float* __restrict__ mem,
    const float* __restrict__ mn2, const float* __restrict__ wskT,
    float* __restrict__ outp)
{
    constexpr int IC = 128, OC = 64, OCCH = 4;
    constexpr int PW = 36, PLANE = 34 * 36;
    const int tx = threadIdx.x & 31;          // col-pair j
    const int ty = threadIdx.x >> 5;          // 0..7
    int zi = blockIdx.z;
    const int ocb = (zi & 15) * OCCH; zi >>= 4;
    const int py = zi & 1;
    const int n  = zi >> 1;
    const int i0 = blockIdx.y * 16 + ty * 2;  // plane rows i0, i0+1

    const unsigned char* sp = s3p + (size_t)n * IC * PLANE + (size_t)(i0 + py) * PW + tx;
    const float* ep = eff + ((size_t)py * OC + ocb) * IC * 8;

    float accA0[OCCH] = {0.f,0.f,0.f,0.f}, accB0[OCCH] = {0.f,0.f,0.f,0.f};
    float accA1[OCCH] = {0.f,0.f,0.f,0.f}, accB1[OCCH] = {0.f,0.f,0.f,0.f};

#pragma unroll 2
    for (int ci = 0; ci < IC; ++ci) {
        const unsigned char* p = sp + (size_t)ci * PLANE;
        float v00 = (float)p[0],      v01 = (float)p[1],      v02 = (float)p[2];
        float v10 = (float)p[PW],     v11 = (float)p[PW+1],   v12 = (float)p[PW+2];
        float v20 = (float)p[2*PW],   v21 = (float)p[2*PW+1], v22 = (float)p[2*PW+2];
#pragma unroll
        for (int oc = 0; oc < OCCH; ++oc) {
            const float* e8 = ep + ((size_t)oc * IC + ci) * 8;
            float e0=e8[0], e1=e8[1], e2=e8[2], e3=e8[3];
            float e4=e8[4], e5=e8[5], e6=e8[6], e7=e8[7];
            accA0[oc] = fmaf(v00,e0, fmaf(v01,e1, fmaf(v10,e2, fmaf(v11,e3, accA0[oc]))));
            accB0[oc] = fmaf(v01,e4, fmaf(v02,e5, fmaf(v11,e6, fmaf(v12,e7, accB0[oc]))));
            accA1[oc] = fmaf(v10,e0, fmaf(v11,e1, fmaf(v20,e2, fmaf(v21,e3, accA1[oc]))));
            accB1[oc] = fmaf(v11,e4, fmaf(v12,e5, fmaf(v21,e6, fmaf(v22,e7, accB1[oc]))));
        }
    }

    const int oy0 = 2 * i0 + py;
    const int ox0 = 2 * tx;

#pragma unroll
    for (int oc = 0; oc < OCCH; ++oc) {
        float bb = b[ocb + oc];
        size_t ia = (((size_t)n * OC + ocb + oc) * 64 + oy0) * 64 + ox0;
        size_t ib = ia + 2 * 64;
        float2 m0 = *(const float2*)(mem + ia);
        float2 m1 = *(const float2*)(mem + ib);
        float cA0 = accA0[oc] + bb, cB0 = accB0[oc] + bb;
        float cA1 = accA1[oc] + bb, cB1 = accB1[oc] + bb;
        float mA0 = m0.x + (cA0 - m0.x) * 0.5f;
        float mB0 = m0.y + (cB0 - m0.y) * 0.5f;
        float mA1 = m1.x + (cA1 - m1.x) * 0.5f;
        float mB1 = m1.y + (cB1 - m1.y) * 0.5f;
        float sA0 = (mA0 > 1.f) ? 1.f : 0.f;
        float sB0 = (mB0 > 1.f) ? 1.f : 0.f;
        float sA1 = (mA1 > 1.f) ? 1.f : 0.f;
        float sB1 = (mB1 > 1.f) ? 1.f : 0.f;
        *(float2*)(mem + ia) = make_float2(mA0 - sA0, mB0 - sB0);
        *(float2*)(mem + ib) = make_float2(mA1 - sA1, mB1 - sB1);
        accA0[oc] = sA0; accB0[oc] = sB0; accA1[oc] = sA1; accB1[oc] = sB1;
    }

#pragma unroll 4
    for (int ci = 0; ci < OC; ++ci) {
        const float* wp = wskT + ci * OC + ocb;
        size_t sbase = (((size_t)n * OC + ci) * 64 + oy0) * 64 + ox0;
        float2 v0 = *(const float2*)(mn2 + sbase);
        float2 v1 = *(const float2*)(mn2 + sbase + 2 * 64);
#pragma unroll
        for (int oc = 0; oc < OCCH; ++oc) {
            accA0[oc] = fmaf(v0.x, wp[oc], accA0[oc]);
            accB0[oc] = fmaf(v0.y, wp[oc], accB0[oc]);
            accA1[oc] = fmaf(v1.x, wp[oc], accA1[oc]);
            accB1[oc] = fmaf(v1.y, wp[oc], accB1[oc]);
        }
    }

#pragma unroll
    for (int oc = 0; oc < OCCH; ++oc) {
        size_t ia = (((size_t)n * OC + ocb + oc) * 64 + oy0) * 64 + ox0;
        *(float2*)(outp + ia)          = make_float2(accA0[oc], accB0[oc]);
        *(float2*)(outp + ia + 2 * 64) = make_float2(accA1[oc], accB1[oc]);
    }
}

// =====================  decoder (d2/d1): upsample2 + conv3x3 + LIF (+1x1 skip)  ==========
template<int IC, int OC, int SRC, int OCCH, int ICCH, bool SKIP, bool SRCU8, bool OUTU8>
__global__ __launch_bounds__(256) void k_dec(
    const void* __restrict__ srcv, const float* __restrict__ eff, const float* __restrict__ b,
    float* __restrict__ mem, const float* __restrict__ mnsk, const float* __restrict__ wskT,
    void* __restrict__ outv, int store_out)
{
    constexpr int OUT = SRC * 2;
    constexpr int TH = 17, TW = 18;
    __shared__ __align__(16) unsigned char smem[ICCH * TH * TW * (SRCU8 ? 1 : 4)];
    unsigned char* tileB = smem;
    float* tileF = (float*)smem;
    const unsigned char* src8 = (const unsigned char*)srcv;
    const float* srcF = (const float*)srcv;

    const int tx = threadIdx.x & 15, ty = threadIdx.x >> 4;
    constexpr int nchunks = OC / OCCH;
    int zi = blockIdx.z;
    const int ocb = (zi % nchunks) * OCCH; zi /= nchunks;
    const int py = zi & 1;
    const int n  = zi >> 1;
    const int i0 = blockIdx.y * 16;
    const int j0 = blockIdx.x * 16;
    const int rbase0 = i0 - 1 + py;
    const int cbase0 = j0 - 1;

    float accA[OCCH], accB[OCCH];
#pragma unroll
    for (int oc = 0; oc < OCCH; ++oc) { accA[oc] = 0.f; accB[oc] = 0.f; }

    for (int icc = 0; icc < IC; icc += ICCH) {
        __syncthreads();
        for (int e = threadIdx.x; e < ICCH * TH * TW; e += 256) {
            int c = e % TW; int r = (e / TW) % TH; int ci = e / (TH * TW);
            int gy = rbase0 + r, gx = cbase0 + c;
            bool ok = (gy >= 0 && gy < SRC && gx >= 0 && gx < SRC);
            size_t gidx = (((size_t)n * IC + icc + ci) * SRC + gy) * SRC + gx;
            if constexpr (SRCU8) tileB[e] = ok ? src8[gidx] : (unsigned char)0;
            else                 tileF[e] = ok ? srcF[gidx] : 0.f;
        }
        __syncthreads();
#pragma unroll 2
        for (int ci = 0; ci < ICCH; ++ci) {
            float s00, s01, s02, s10, s11, s12;
            const int base = (ci * TH + ty) * TW + tx;
            if constexpr (SRCU8) {
                s00 = (float)tileB[base];      s01 = (float)tileB[base + 1];      s02 = (float)tileB[base + 2];
                s10 = (float)tileB[base + TW]; s11 = (float)tileB[base + TW + 1]; s12 = (float)tileB[base + TW + 2];
            } else {
                s00 = tileF[base];      s01 = tileF[base + 1];      s02 = tileF[base + 2];
                s10 = tileF[base + TW]; s11 = tileF[base + TW + 1]; s12 = tileF[base + TW + 2];
            }
#pragma unroll
            for (int oc = 0; oc < OCCH; ++oc) {
                const float* e8 = eff + ((((size_t)py * OC + ocb + oc) * IC) + icc + ci) * 8;
                accA[oc] = fmaf(s00, e8[0], accA[oc]);
                accA[oc] = fmaf(s01, e8[1], accA[oc]);
                accA[oc] = fmaf(s10, e8[2], accA[oc]);
                accA[oc] = fmaf(s11, e8[3], accA[oc]);
                accB[oc] = fmaf(s01, e8[4], accB[oc]);
                accB[oc] = fmaf(s02, e8[5], accB[oc]);
                accB[oc] = fmaf(s11, e8[6], accB[oc]);
                accB[oc] = fmaf(s12, e8[7], accB[oc]);
            }
        }
    }

    const int oy  = 2 * (i0 + ty) + py;
    const int ox0 = 2 * (j0 + tx);

#pragma unroll
    for (int oc = 0; oc < OCCH; ++oc) {
        int ocg = ocb + oc;
        size_t idx = (((size_t)n * OC + ocg) * OUT + oy) * OUT + ox0;
        float2 mv = *(const float2*)(mem + idx);
        float bb = b[ocg];
        float cA = accA[oc] + bb, cB = accB[oc] + bb;
        float mA = mv.x + (cA - mv.x) * 0.5f;
        float mB = mv.y + (cB - mv.y) * 0.5f;
        float sA = (mA > 1.f) ? 1.f : 0.f;
        float sB = (mB > 1.f) ? 1.f : 0.f;
        *(float2*)(mem + idx) = make_float2(mA - sA, mB - sB);
        accA[oc] = sA; accB[oc] = sB;
    }

    if constexpr (SKIP) {
#pragma unroll 4
        for (int ci = 0; ci < OC; ++ci) {
            size_t sidx = (((size_t)n * OC + ci) * OUT + oy) * OUT + ox0;
            float2 v = *(const float2*)(mnsk + sidx);
            const float* wp = wskT + ci * OC + ocb;
#pragma unroll
            for (int oc = 0; oc < OCCH; ++oc) {
                accA[oc] = fmaf(v.x, wp[oc], accA[oc]);
                accB[oc] = fmaf(v.y, wp[oc], accB[oc]);
            }
        }
    }

    if (store_out) {
#pragma unroll
        for (int oc = 0; oc < OCCH; ++oc) {
            int ocg = ocb + oc;
            size_t idx = (((size_t)n * OC + ocg) * OUT + oy) * OUT + ox0;
            if constexpr (OUTU8) {
                unsigned char* o8 = (unsigned char*)outv;
                o8[idx]     = (unsigned char)accA[oc];
                o8[idx + 1] = (unsigned char)accB[oc];
            } else {
                *(float2*)((float*)outv + idx) = make_float2(accA[oc], accB[oc]);
            }
        }
    }
}

// =====================  final flow conv (3x3 s1 p1, 32->2, *16)  =====================
__global__ __launch_bounds__(256) void k_flow(
    const unsigned char* __restrict__ d1, const float* __restrict__ wT, const float* __restrict__ b,
    float* __restrict__ out)
{
    constexpr int HW = 256;
    __shared__ unsigned char tile[32 * 18 * 19];
    const int tx = threadIdx.x & 15, ty = threadIdx.x >> 4;
    const int n = blockIdx.z;
    const int oy0 = blockIdx.y * 16, ox0 = blockIdx.x * 16;

    for (int e = threadIdx.x; e < 32 * 18 * 18; e += 256) {
        int c = e % 18; int r = (e / 18) % 18; int ci = e / (18 * 18);
        int gy = oy0 - 1 + r, gx = ox0 - 1 + c;
        unsigned char v = 0;
        if (gy >= 0 && gy < HW && gx >= 0 && gx < HW)
            v = d1[(((size_t)n * 32 + ci) * HW + gy) * HW + gx];
        tile[(ci * 18 + r) * 19 + c] = v;
    }
    __syncthreads();

    float a0 = b[0], a1 = b[1];
#pragma unroll 2
    for (int ci = 0; ci < 32; ++ci)
#pragma unroll
        for (int ky = 0; ky < 3; ++ky)
#pragma unroll
            for (int kx = 0; kx < 3; ++kx) {
                float v = (float)tile[(ci * 18 + ty + ky) * 19 + tx + kx];
                const float* wp = wT + ((ci * 3 + ky) * 3 + kx) * 2;
                a0 = fmaf(v, wp[0], a0);
                a1 = fmaf(v, wp[1], a1);
            }

    const int oy = oy0 + ty, ox = ox0 + tx;
    out[(((size_t)n * 2 + 0) * HW + oy) * HW + ox] = a0 * 16.f;
    out[(((size_t)n * 2 + 1) * HW + oy) * HW + ox] = a1 * 16.f;
}

// =====================  launch  =====================
extern "C" void kernel_launch(void* const* d_in, const int* in_sizes, int n_in,
                              void* d_out, int out_size, void* d_ws, size_t ws_size,
                              hipStream_t stream)
{
    const float* x     = (const float*)d_in[0];
    const float* w_e1  = (const float*)d_in[1];
    const float* b_e1  = (const float*)d_in[2];
    const float* w_e2  = (const float*)d_in[3];
    const float* b_e2  = (const float*)d_in[4];
    const float* w_e3  = (const float*)d_in[5];
    const float* b_e3  = (const float*)d_in[6];
    const float* w_d3  = (const float*)d_in[7];
    const float* b_d3  = (const float*)d_in[8];
    const float* w_d2  = (const float*)d_in[9];
    const float* b_d2  = (const float*)d_in[10];
    const float* w_d1  = (const float*)d_in[11];
    const float* b_d1  = (const float*)d_in[12];
    const float* w_sk2 = (const float*)d_in[13];
    const float* w_sk1 = (const float*)d_in[14];
    const float* w_fl  = (const float*)d_in[15];
    const float* b_fl  = (const float*)d_in[16];

    char* ws = (char*)d_ws;
    float* me1 = (float*)(ws + O_ME1);
    float* me2 = (float*)(ws + O_ME2);
    float* me3 = (float*)(ws + O_ME3);
    float* md3 = (float*)(ws + O_MD3);
    float* md2 = (float*)(ws + O_MD2);
    float* md1 = (float*)(ws + O_MD1);
    float* mn1 = (float*)(ws + O_MN1);
    float* mn2 = (float*)(ws + O_MN2);
    unsigned char* s3p = (unsigned char*)(ws + O_S3P);
    unsigned char* s1  = (unsigned char*)(ws + O_S1);
    unsigned char* s2  = (unsigned char*)(ws + O_S2);
    float* d3f = (float*)(ws + O_D3F);
    float* d2f = (float*)(ws + O_D2F);
    unsigned char* d1u = (unsigned char*)(ws + O_D1U);
    float* eff3 = (float*)(ws + O_EFF3);
    float* eff2 = (float*)(ws + O_EFF2);
    float* eff1 = (float*)(ws + O_EFF1);
    float* wTe1 = (float*)(ws + O_WTE1);
    float* wTe2 = (float*)(ws + O_WTE2);
    float* wTe3 = (float*)(ws + O_WTE3);
    float* wTfl = (float*)(ws + O_WTFL);
    float* wsk2 = (float*)(ws + O_WSK2);
    float* wsk1 = (float*)(ws + O_WSK1);

    // zero membranes / means / padded-s3 (pad must stay 0; interiors rewritten each step)
    hipMemsetAsync(d_ws, 0, ZERO_BYTES, stream);

    // prepass
    k_transpose_w<32, 2, 5><<<(1600 + 255) / 256, 256, 0, stream>>>(w_e1, wTe1);
    k_transpose_w<64, 32, 3><<<(18432 + 255) / 256, 256, 0, stream>>>(w_e2, wTe2);
    k_transpose_w<128, 64, 3><<<(73728 + 255) / 256, 256, 0, stream>>>(w_e3, wTe3);
    k_transpose_w<2, 32, 3><<<(576 + 255) / 256, 256, 0, stream>>>(w_fl, wTfl);
    k_transpose_w<64, 64, 1><<<(4096 + 255) / 256, 256, 0, stream>>>(w_sk2, wsk2);
    k_transpose_w<32, 32, 1><<<(1024 + 255) / 256, 256, 0, stream>>>(w_sk1, wsk1);
    k_eff<64, 128><<<(2 * 64 * 128 + 255) / 256, 256, 0, stream>>>(w_d3, eff3);
    k_eff<32, 64><<<(2 * 32 * 64 + 255) / 256, 256, 0, stream>>>(w_d2, eff2);
    k_eff<32, 32><<<(2 * 32 * 32 + 255) / 256, 256, 0, stream>>>(w_d1, eff1);

    for (int t = 0; t < TSTEPS; ++t) {
        float inv = 1.0f / (float)(t + 1);
        k_e1<16><<<dim3(8, 8, NB * 2), 256, 0, stream>>>(x, wTe1, b_e1, me1, mn1, s1, t, inv);
        k_enc<32, 64, 64, 8, true, false><<<dim3(4, 4, NB * 8), 256, 0, stream>>>(
            s1, wTe2, b_e2, me2, mn2, s2, inv);
        k_enc<64, 128, 32, 4, false, true><<<dim3(2, 2, NB * 32), 256, 0, stream>>>(
            s2, wTe3, b_e3, me3, (float*)nullptr, s3p, 0.f);
        k_dec3<<<dim3(1, 2, NB * 2 * 16), 256, 0, stream>>>(
            s3p, eff3, b_d3, md3, mn2, wsk2, d3f);
        k_dec<64, 32, 64, 8, 16, true, false, false><<<dim3(4, 4, NB * 2 * 4), 256, 0, stream>>>(
            d3f, eff2, b_d2, md2, mn1, wsk1, d2f, 1);
        k_dec<32, 32, 128, 8, 16, false, false, true><<<dim3(8, 8, NB * 2 * 4), 256, 0, stream>>>(
            d2f, eff1, b_d1, md1, (const float*)nullptr, (const float*)nullptr, d1u,
            (t == TSTEPS - 1) ? 1 : 0);
    }
    k_flow<<<dim3(16, 16, NB), 256, 0, stream>>>(d1u, wTfl, b_fl, (float*)d_out);
}

// Round 11
// 3169.016 us; speedup vs baseline: 1.9224x; 1.4714x over previous
//
#include <hip/hip_runtime.h>

// =====================  problem constants  =====================
constexpr int NB = 8;        // batch
constexpr int TSTEPS = 10;   // timesteps

// =====================  workspace layout (bytes)  =====================
constexpr size_t SZ_ME1 = (size_t)NB*32*128*128*4;
constexpr size_t SZ_ME2 = (size_t)NB*64*64*64*4;
constexpr size_t SZ_ME3 = (size_t)NB*128*32*32*4;
constexpr size_t SZ_MD3 = SZ_ME2;
constexpr size_t SZ_MD2 = SZ_ME1;
constexpr size_t SZ_MD1 = (size_t)NB*32*256*256*4;
constexpr size_t SZ_MN1 = SZ_ME1;
constexpr size_t SZ_MN2 = SZ_ME2;
// zero-padded activation planes (pads must stay 0; interiors rewritten each step)
constexpr size_t SZ_S1P  = (size_t)NB*32*130*132;      // e1 spikes u8, interior (+1,+1)
constexpr size_t SZ_S2P  = (size_t)NB*64*66*68;        // e2 spikes u8, interior (+1,+1)
constexpr size_t SZ_S3P  = (size_t)NB*128*34*36;       // e3 spikes u8, interior (+1,+1)
constexpr size_t SZ_D3FP = (size_t)NB*64*66*68*4;      // d3 out float, interior (+1,+2)
constexpr size_t SZ_D2FP = (size_t)NB*32*130*132*4;    // d2 out float, interior (+1,+2)

constexpr size_t O_ME1 = 0;
constexpr size_t O_ME2 = O_ME1 + SZ_ME1;
constexpr size_t O_ME3 = O_ME2 + SZ_ME2;
constexpr size_t O_MD3 = O_ME3 + SZ_ME3;
constexpr size_t O_MD2 = O_MD3 + SZ_MD3;
constexpr size_t O_MD1 = O_MD2 + SZ_MD2;
constexpr size_t O_MN1 = O_MD1 + SZ_MD1;
constexpr size_t O_MN2 = O_MN1 + SZ_MN1;
constexpr size_t O_S1P  = O_MN2 + SZ_MN2;
constexpr size_t O_S2P  = O_S1P + SZ_S1P;
constexpr size_t O_S3P  = O_S2P + SZ_S2P;
constexpr size_t O_D3FP = O_S3P + SZ_S3P;
constexpr size_t O_D2FP = O_D3FP + SZ_D3FP;
constexpr size_t ZERO_BYTES = O_D2FP + SZ_D2FP;        // ~181.5 MB zeroed each launch

// d1u (u8, 16.78MB) ALIASES s1p..d3fp (17.14MB): written only at t=9, after all
// readers of s1p/s2p/s3p/d3fp for that step have completed (stream-ordered).
constexpr size_t O_D1U = O_S1P;
static_assert(SZ_S1P + SZ_S2P + SZ_S3P + SZ_D3FP >= (size_t)NB*32*256*256, "alias fits");

constexpr size_t O_EFF3 = ZERO_BYTES;                  // eff tables (float)
constexpr size_t O_EFF2 = O_EFF3 + (size_t)2*64*128*8*4;
constexpr size_t O_EFF1 = O_EFF2 + (size_t)2*32*64*8*4;
constexpr size_t O_WTE1 = O_EFF1 + (size_t)2*32*32*8*4; // transposed weights
constexpr size_t O_WTE2 = O_WTE1 + (size_t)2*5*5*32*4;
constexpr size_t O_WTE3 = O_WTE2 + (size_t)32*3*3*64*4;
constexpr size_t O_WTFL = O_WTE3 + (size_t)64*3*3*128*4;
constexpr size_t O_WSK2 = O_WTFL + (size_t)32*3*3*2*4;
constexpr size_t O_WSK1 = O_WSK2 + (size_t)64*64*4;
// end: ~182.3 MiB (< 197 MiB proven-good)

// =====================  prepass kernels  =====================
template<int OC, int IC, int K>
__global__ void k_transpose_w(const float* __restrict__ w, float* __restrict__ wT) {
    int i = blockIdx.x * 256 + threadIdx.x;
    constexpr int total = OC * IC * K * K;
    if (i >= total) return;
    int oc = i % OC; int r = i / OC;
    int kx = r % K;  r /= K;
    int ky = r % K;  r /= K;
    int ci = r;
    wT[i] = w[((oc * IC + ci) * K + ky) * K + kx];
}

// eff[((py*OC+oc)*IC+ci)*8 + (px*4 + di*2 + dj)]
template<int OC, int IC>
__global__ void k_eff(const float* __restrict__ w, float* __restrict__ eff) {
    int i = blockIdx.x * 256 + threadIdx.x;
    constexpr int total = 2 * OC * IC;
    if (i >= total) return;
    int ci = i % IC; int r = i / IC;
    int oc = r % OC; int py = r / OC;
    const float* wp = w + ((size_t)oc * IC + ci) * 9;
    float w00=wp[0],w01=wp[1],w02=wp[2],w10=wp[3],w11=wp[4],w12=wp[5],w20=wp[6],w21=wp[7],w22=wp[8];
    float r0c0,r0c1,r0c2,r1c0,r1c1,r1c2;
    if (py == 0) { r0c0=w00;     r0c1=w01;     r0c2=w02;     r1c0=w10+w20; r1c1=w11+w21; r1c2=w12+w22; }
    else         { r0c0=w00+w10; r0c1=w01+w11; r0c2=w02+w12; r1c0=w20;     r1c1=w21;     r1c2=w22;     }
    float* e = eff + (size_t)i * 8;
    e[0] = r0c0;        e[1] = r0c1 + r0c2;   // px=0
    e[2] = r1c0;        e[3] = r1c1 + r1c2;
    e[4] = r0c0 + r0c1; e[5] = r0c2;          // px=1
    e[6] = r1c0 + r1c1; e[7] = r1c2;
}

// =====================  e1: 5x5 s2 p2 conv + LIF (fp32 input, LDS tile)  ============
template<int OCCH>
__global__ __launch_bounds__(256) void k_e1(
    const float* __restrict__ x, const float* __restrict__ wT, const float* __restrict__ b,
    float* __restrict__ me1, float* __restrict__ mn1, unsigned char* __restrict__ s1p,
    int t, float inv)
{
    __shared__ float tile[2 * 35 * 36];
    const int tx = threadIdx.x & 15, ty = threadIdx.x >> 4;
    constexpr int nchunks = 32 / OCCH;
    int zi = blockIdx.z;
    const int ocb = (zi % nchunks) * OCCH;
    const int n = zi / nchunks;
    const int oy0 = blockIdx.y * 16, ox0 = blockIdx.x * 16;
    const int iy0 = oy0 * 2 - 2, ix0 = ox0 * 2 - 2;

    for (int e = threadIdx.x; e < 2 * 35 * 35; e += 256) {
        int c = e % 35; int r = (e / 35) % 35; int ci = e / (35 * 35);
        int gy = iy0 + r, gx = ix0 + c;
        float v = 0.f;
        if (gy >= 0 && gy < 256 && gx >= 0 && gx < 256)
            v = x[((((size_t)n * TSTEPS + t) * 2 + ci) * 256 + gy) * 256 + gx];
        tile[(ci * 35 + r) * 36 + c] = v;
    }
    __syncthreads();

    float acc[OCCH];
#pragma unroll
    for (int oc = 0; oc < OCCH; ++oc) acc[oc] = b[ocb + oc];
#pragma unroll
    for (int ci = 0; ci < 2; ++ci)
#pragma unroll
        for (int ky = 0; ky < 5; ++ky)
#pragma unroll
            for (int kx = 0; kx < 5; ++kx) {
                float v = tile[(ci * 35 + ty * 2 + ky) * 36 + tx * 2 + kx];
                const float* wp = wT + ((ci * 5 + ky) * 5 + kx) * 32 + ocb;
#pragma unroll
                for (int oc = 0; oc < OCCH; ++oc) acc[oc] = fmaf(v, wp[oc], acc[oc]);
            }

    const int oy = oy0 + ty, ox = ox0 + tx;
#pragma unroll
    for (int oc = 0; oc < OCCH; ++oc) {
        size_t idx = (((size_t)n * 32 + ocb + oc) * 128 + oy) * 128 + ox;
        float mo = me1[idx];
        float m  = mo + (acc[oc] - mo) * 0.5f;
        float s  = (m > 1.0f) ? 1.0f : 0.0f;
        me1[idx] = m - s;
        float mn = mn1[idx];
        mn1[idx] = mn + (s - mn) * inv;
        s1p[((size_t)(n * 32 + ocb + oc) * 130 + 1 + oy) * 132 + 1 + ox] = (unsigned char)s;
    }
}

// =====================  e2/e3: stride-2 3x3 conv + LIF, direct-global  ===============
// Input: zero-padded u8 planes [PIN_H=2*OUT+2][PIN_W], interior at (+1,+1).
// Output: spikes into zero-padded u8 planes [POUT_H][POUT_W], interior (+1,+1).
template<int IC, int OC, int OUT, int OCCH, bool MEAN, int PIN_W, int POUT_H, int POUT_W>
__global__ __launch_bounds__(256) void k_enc2(
    const unsigned char* __restrict__ sinp, const float* __restrict__ wT, const float* __restrict__ b,
    float* __restrict__ mem, float* __restrict__ mn, unsigned char* __restrict__ soutp, float inv)
{
    constexpr int PIN_H = 2 * OUT + 2;
    constexpr int PIN_PLANE = PIN_H * PIN_W;
    constexpr int RPB = 256 / OUT;              // rows per block
    constexpr int nchunks = OC / OCCH;
    const int tx = (int)threadIdx.x % OUT;
    const int ty = (int)threadIdx.x / OUT;
    int zi = blockIdx.z;
    const int ocb = (zi % nchunks) * OCCH;
    const int n = zi / nchunks;
    const int oy = blockIdx.y * RPB + ty;
    const int ox = tx;

    // padded window rows 2oy..2oy+2 (input 2oy-1..2oy+1), cols 2ox..2ox+2
    const unsigned char* sp = sinp + (size_t)n * IC * PIN_PLANE + (size_t)(2 * oy) * PIN_W + 2 * ox;
    const float* wbase = wT + ocb;

    float acc[OCCH];
#pragma unroll
    for (int oc = 0; oc < OCCH; ++oc) acc[oc] = b[ocb + oc];

#pragma unroll 2
    for (int ci = 0; ci < IC; ++ci) {
        const unsigned char* p = sp + (size_t)ci * PIN_PLANE;
        float v00 = (float)p[0],          v01 = (float)p[1],          v02 = (float)p[2];
        float v10 = (float)p[PIN_W],      v11 = (float)p[PIN_W + 1],  v12 = (float)p[PIN_W + 2];
        float v20 = (float)p[2 * PIN_W],  v21 = (float)p[2 * PIN_W + 1], v22 = (float)p[2 * PIN_W + 2];
        const float* w0 = wbase + (size_t)(ci * 9 + 0) * OC;
        const float* w1 = wbase + (size_t)(ci * 9 + 1) * OC;
        const float* w2 = wbase + (size_t)(ci * 9 + 2) * OC;
        const float* w3 = wbase + (size_t)(ci * 9 + 3) * OC;
        const float* w4 = wbase + (size_t)(ci * 9 + 4) * OC;
        const float* w5 = wbase + (size_t)(ci * 9 + 5) * OC;
        const float* w6 = wbase + (size_t)(ci * 9 + 6) * OC;
        const float* w7 = wbase + (size_t)(ci * 9 + 7) * OC;
        const float* w8 = wbase + (size_t)(ci * 9 + 8) * OC;
#pragma unroll
        for (int oc = 0; oc < OCCH; ++oc) {
            float a = acc[oc];
            a = fmaf(v00, w0[oc], a); a = fmaf(v01, w1[oc], a); a = fmaf(v02, w2[oc], a);
            a = fmaf(v10, w3[oc], a); a = fmaf(v11, w4[oc], a); a = fmaf(v12, w5[oc], a);
            a = fmaf(v20, w6[oc], a); a = fmaf(v21, w7[oc], a); a = fmaf(v22, w8[oc], a);
            acc[oc] = a;
        }
    }

#pragma unroll
    for (int oc = 0; oc < OCCH; ++oc) {
        size_t idx = (((size_t)n * OC + ocb + oc) * OUT + oy) * OUT + ox;
        float mo = mem[idx];
        float m  = mo + (acc[oc] - mo) * 0.5f;
        float s  = (m > 1.0f) ? 1.0f : 0.0f;
        mem[idx] = m - s;
        if constexpr (MEAN) { float mv = mn[idx]; mn[idx] = mv + (s - mv) * inv; }
        soutp[((size_t)(n * OC + ocb + oc) * POUT_H + 1 + oy) * POUT_W + 1 + ox] = (unsigned char)s;
    }
}

// =====================  d3: direct-global decoder (u8 in, padded-float out)  =========
__global__ __launch_bounds__(256) void k_dec3(
    const unsigned char* __restrict__ s3p, const float* __restrict__ eff,
    const float* __restrict__ b, float* __restrict__ mem,
    const float* __restrict__ mn2, const float* __restrict__ wskT,
    float* __restrict__ outp)
{
    constexpr int IC = 128, OC = 64, OCCH = 4;
    constexpr int PW = 36, PLANE = 34 * 36;
    const int tx = threadIdx.x & 31;          // col-pair j
    const int ty = threadIdx.x >> 5;          // 0..7
    int zi = blockIdx.z;
    const int ocb = (zi & 15) * OCCH; zi >>= 4;
    const int py = zi & 1;
    const int n  = zi >> 1;
    const int i0 = blockIdx.y * 16 + ty * 2;  // plane rows i0, i0+1

    const unsigned char* sp = s3p + (size_t)n * IC * PLANE + (size_t)(i0 + py) * PW + tx;
    const float* ep = eff + ((size_t)py * OC + ocb) * IC * 8;

    float accA0[OCCH] = {0.f,0.f,0.f,0.f}, accB0[OCCH] = {0.f,0.f,0.f,0.f};
    float accA1[OCCH] = {0.f,0.f,0.f,0.f}, accB1[OCCH] = {0.f,0.f,0.f,0.f};

#pragma unroll 2
    for (int ci = 0; ci < IC; ++ci) {
        const unsigned char* p = sp + (size_t)ci * PLANE;
        float v00 = (float)p[0],      v01 = (float)p[1],      v02 = (float)p[2];
        float v10 = (float)p[PW],     v11 = (float)p[PW+1],   v12 = (float)p[PW+2];
        float v20 = (float)p[2*PW],   v21 = (float)p[2*PW+1], v22 = (float)p[2*PW+2];
#pragma unroll
        for (int oc = 0; oc < OCCH; ++oc) {
            const float* e8 = ep + ((size_t)oc * IC + ci) * 8;
            float e0=e8[0], e1=e8[1], e2=e8[2], e3=e8[3];
            float e4=e8[4], e5=e8[5], e6=e8[6], e7=e8[7];
            accA0[oc] = fmaf(v00,e0, fmaf(v01,e1, fmaf(v10,e2, fmaf(v11,e3, accA0[oc]))));
            accB0[oc] = fmaf(v01,e4, fmaf(v02,e5, fmaf(v11,e6, fmaf(v12,e7, accB0[oc]))));
            accA1[oc] = fmaf(v10,e0, fmaf(v11,e1, fmaf(v20,e2, fmaf(v21,e3, accA1[oc]))));
            accB1[oc] = fmaf(v11,e4, fmaf(v12,e5, fmaf(v21,e6, fmaf(v22,e7, accB1[oc]))));
        }
    }

    const int oy0 = 2 * i0 + py;
    const int ox0 = 2 * tx;

#pragma unroll
    for (int oc = 0; oc < OCCH; ++oc) {
        float bb = b[ocb + oc];
        size_t ia = (((size_t)n * OC + ocb + oc) * 64 + oy0) * 64 + ox0;
        size_t ib = ia + 2 * 64;
        float2 m0 = *(const float2*)(mem + ia);
        float2 m1 = *(const float2*)(mem + ib);
        float cA0 = accA0[oc] + bb, cB0 = accB0[oc] + bb;
        float cA1 = accA1[oc] + bb, cB1 = accB1[oc] + bb;
        float mA0 = m0.x + (cA0 - m0.x) * 0.5f;
        float mB0 = m0.y + (cB0 - m0.y) * 0.5f;
        float mA1 = m1.x + (cA1 - m1.x) * 0.5f;
        float mB1 = m1.y + (cB1 - m1.y) * 0.5f;
        float sA0 = (mA0 > 1.f) ? 1.f : 0.f;
        float sB0 = (mB0 > 1.f) ? 1.f : 0.f;
        float sA1 = (mA1 > 1.f) ? 1.f : 0.f;
        float sB1 = (mB1 > 1.f) ? 1.f : 0.f;
        *(float2*)(mem + ia) = make_float2(mA0 - sA0, mB0 - sB0);
        *(float2*)(mem + ib) = make_float2(mA1 - sA1, mB1 - sB1);
        accA0[oc] = sA0; accB0[oc] = sB0; accA1[oc] = sA1; accB1[oc] = sB1;
    }

#pragma unroll 4
    for (int ci = 0; ci < OC; ++ci) {
        const float* wp = wskT + ci * OC + ocb;
        size_t sbase = (((size_t)n * OC + ci) * 64 + oy0) * 64 + ox0;
        float2 v0 = *(const float2*)(mn2 + sbase);
        float2 v1 = *(const float2*)(mn2 + sbase + 2 * 64);
#pragma unroll
        for (int oc = 0; oc < OCCH; ++oc) {
            accA0[oc] = fmaf(v0.x, wp[oc], accA0[oc]);
            accB0[oc] = fmaf(v0.y, wp[oc], accB0[oc]);
            accA1[oc] = fmaf(v1.x, wp[oc], accA1[oc]);
            accB1[oc] = fmaf(v1.y, wp[oc], accB1[oc]);
        }
    }

    // store to padded d3fp [66][68], interior (+1,+2); ox0 even -> 8B aligned
#pragma unroll
    for (int oc = 0; oc < OCCH; ++oc) {
        size_t ob = ((size_t)(n * OC + ocb + oc) * 66 + (oy0 + 1)) * 68 + (ox0 + 2);
        *(float2*)(outp + ob)          = make_float2(accA0[oc], accB0[oc]);
        *(float2*)(outp + ob + 2 * 68) = make_float2(accA1[oc], accB1[oc]);
    }
}

// =====================  d2/d1: direct-global decoder (padded-float in)  ==============
// Input: padded float [SRC+2][PIN_W], interior (+1,+2).
// d2: SKIP over mnsk/wskT, padded-float out [POUT_H][POUT_W] interior (+1,+2).
// d1: no skip, u8 unpadded out (only when store_out).
template<int IC, int OC, int SRC, bool SKIP, bool OUTU8, int PIN_W, int POUT_H, int POUT_W>
__global__ __launch_bounds__(256) void k_decf(
    const float* __restrict__ sinp, const float* __restrict__ eff, const float* __restrict__ b,
    float* __restrict__ mem, const float* __restrict__ mnsk, const float* __restrict__ wskT,
    void* __restrict__ outv, int store_out)
{
    constexpr int OCCH = 4;
    constexpr int OUT = SRC * 2;
    constexpr int PIN_H = SRC + 2;
    constexpr int PIN_PLANE = PIN_H * PIN_W;
    constexpr int nchunks = OC / OCCH;
    const int tx = (int)threadIdx.x & 63;
    const int ty = (int)threadIdx.x >> 6;      // 0..3
    const int J = blockIdx.x * 64 + tx;        // col-pair
    int zi = blockIdx.z;
    const int ocb = (zi % nchunks) * OCCH; zi /= nchunks;
    const int py = zi & 1;
    const int n  = zi >> 1;
    const int i0 = blockIdx.y * 8 + ty * 2;    // plane rows i0, i0+1

    const float* sp = sinp + (size_t)n * IC * PIN_PLANE + (size_t)(i0 + py) * PIN_W + (J + 1);
    const float* ep = eff + ((size_t)py * OC + ocb) * IC * 8;

    float accA0[OCCH] = {0.f,0.f,0.f,0.f}, accB0[OCCH] = {0.f,0.f,0.f,0.f};
    float accA1[OCCH] = {0.f,0.f,0.f,0.f}, accB1[OCCH] = {0.f,0.f,0.f,0.f};

#pragma unroll 2
    for (int ci = 0; ci < IC; ++ci) {
        const float* p = sp + (size_t)ci * PIN_PLANE;
        float v00 = p[0],          v01 = p[1],          v02 = p[2];
        float v10 = p[PIN_W],      v11 = p[PIN_W + 1],  v12 = p[PIN_W + 2];
        float v20 = p[2 * PIN_W],  v21 = p[2 * PIN_W + 1], v22 = p[2 * PIN_W + 2];
#pragma unroll
        for (int oc = 0; oc < OCCH; ++oc) {
            const float* e8 = ep + ((size_t)oc * IC + ci) * 8;
            float e0=e8[0], e1=e8[1], e2=e8[2], e3=e8[3];
            float e4=e8[4], e5=e8[5], e6=e8[6], e7=e8[7];
            accA0[oc] = fmaf(v00,e0, fmaf(v01,e1, fmaf(v10,e2, fmaf(v11,e3, accA0[oc]))));
            accB0[oc] = fmaf(v01,e4, fmaf(v02,e5, fmaf(v11,e6, fmaf(v12,e7, accB0[oc]))));
            accA1[oc] = fmaf(v10,e0, fmaf(v11,e1, fmaf(v20,e2, fmaf(v21,e3, accA1[oc]))));
            accB1[oc] = fmaf(v11,e4, fmaf(v12,e5, fmaf(v21,e6, fmaf(v22,e7, accB1[oc]))));
        }
    }

    const int oy0 = 2 * i0 + py;
    const int ox0 = 2 * J;

#pragma unroll
    for (int oc = 0; oc < OCCH; ++oc) {
        float bb = b[ocb + oc];
        size_t ia = (((size_t)n * OC + ocb + oc) * OUT + oy0) * OUT + ox0;
        size_t ib = ia + 2 * OUT;
        float2 m0 = *(const float2*)(mem + ia);
        float2 m1 = *(const float2*)(mem + ib);
        float cA0 = accA0[oc] + bb, cB0 = accB0[oc] + bb;
        float cA1 = accA1[oc] + bb, cB1 = accB1[oc] + bb;
        float mA0 = m0.x + (cA0 - m0.x) * 0.5f;
        float mB0 = m0.y + (cB0 - m0.y) * 0.5f;
        float mA1 = m1.x + (cA1 - m1.x) * 0.5f;
        float mB1 = m1.y + (cB1 - m1.y) * 0.5f;
        float sA0 = (mA0 > 1.f) ? 1.f : 0.f;
        float sB0 = (mB0 > 1.f) ? 1.f : 0.f;
        float sA1 = (mA1 > 1.f) ? 1.f : 0.f;
        float sB1 = (mB1 > 1.f) ? 1.f : 0.f;
        *(float2*)(mem + ia) = make_float2(mA0 - sA0, mB0 - sB0);
        *(float2*)(mem + ib) = make_float2(mA1 - sA1, mB1 - sB1);
        accA0[oc] = sA0; accB0[oc] = sB0; accA1[oc] = sA1; accB1[oc] = sB1;
    }

    if constexpr (SKIP) {
#pragma unroll 4
        for (int ci = 0; ci < OC; ++ci) {
            const float* wp = wskT + ci * OC + ocb;
            size_t sbase = (((size_t)n * OC + ci) * OUT + oy0) * OUT + ox0;
            float2 v0 = *(const float2*)(mnsk + sbase);
            float2 v1 = *(const float2*)(mnsk + sbase + 2 * OUT);
#pragma unroll
            for (int oc = 0; oc < OCCH; ++oc) {
                accA0[oc] = fmaf(v0.x, wp[oc], accA0[oc]);
                accB0[oc] = fmaf(v0.y, wp[oc], accB0[oc]);
                accA1[oc] = fmaf(v1.x, wp[oc], accA1[oc]);
                accB1[oc] = fmaf(v1.y, wp[oc], accB1[oc]);
            }
        }
    }

    if constexpr (OUTU8) {
        if (store_out) {
            unsigned char* o8 = (unsigned char*)outv;
#pragma unroll
            for (int oc = 0; oc < OCCH; ++oc) {
                size_t ob = (((size_t)n * OC + ocb + oc) * OUT + oy0) * OUT + ox0;
                o8[ob]               = (unsigned char)accA0[oc];
                o8[ob + 1]           = (unsigned char)accB0[oc];
                o8[ob + 2 * OUT]     = (unsigned char)accA1[oc];
                o8[ob + 2 * OUT + 1] = (unsigned char)accB1[oc];
            }
        }
    } else {
        float* of = (float*)outv;
#pragma unroll
        for (int oc = 0; oc < OCCH; ++oc) {
            size_t ob = ((size_t)(n * OC + ocb + oc) * POUT_H + (oy0 + 1)) * POUT_W + (ox0 + 2);
            *(float2*)(of + ob)              = make_float2(accA0[oc], accB0[oc]);
            *(float2*)(of + ob + 2 * POUT_W) = make_float2(accA1[oc], accB1[oc]);
        }
    }
}

// =====================  final flow conv (3x3 s1 p1, 32->2, *16)  =====================
__global__ __launch_bounds__(256) void k_flow(
    const unsigned char* __restrict__ d1, const float* __restrict__ wT, const float* __restrict__ b,
    float* __restrict__ out)
{
    constexpr int HW = 256;
    __shared__ unsigned char tile[32 * 18 * 19];
    const int tx = threadIdx.x & 15, ty = threadIdx.x >> 4;
    const int n = blockIdx.z;
    const int oy0 = blockIdx.y * 16, ox0 = blockIdx.x * 16;

    for (int e = threadIdx.x; e < 32 * 18 * 18; e += 256) {
        int c = e % 18; int r = (e / 18) % 18; int ci = e / (18 * 18);
        int gy = oy0 - 1 + r, gx = ox0 - 1 + c;
        unsigned char v = 0;
        if (gy >= 0 && gy < HW && gx >= 0 && gx < HW)
            v = d1[(((size_t)n * 32 + ci) * HW + gy) * HW + gx];
        tile[(ci * 18 + r) * 19 + c] = v;
    }
    __syncthreads();

    float a0 = b[0], a1 = b[1];
#pragma unroll 2
    for (int ci = 0; ci < 32; ++ci)
#pragma unroll
        for (int ky = 0; ky < 3; ++ky)
#pragma unroll
            for (int kx = 0; kx < 3; ++kx) {
                float v = (float)tile[(ci * 18 + ty + ky) * 19 + tx + kx];
                const float* wp = wT + ((ci * 3 + ky) * 3 + kx) * 2;
                a0 = fmaf(v, wp[0], a0);
                a1 = fmaf(v, wp[1], a1);
            }

    const int oy = oy0 + ty, ox = ox0 + tx;
    out[(((size_t)n * 2 + 0) * HW + oy) * HW + ox] = a0 * 16.f;
    out[(((size_t)n * 2 + 1) * HW + oy) * HW + ox] = a1 * 16.f;
}

// =====================  launch  =====================
extern "C" void kernel_launch(void* const* d_in, const int* in_sizes, int n_in,
                              void* d_out, int out_size, void* d_ws, size_t ws_size,
                              hipStream_t stream)
{
    const float* x     = (const float*)d_in[0];
    const float* w_e1  = (const float*)d_in[1];
    const float* b_e1  = (const float*)d_in[2];
    const float* w_e2  = (const float*)d_in[3];
    const float* b_e2  = (const float*)d_in[4];
    const float* w_e3  = (const float*)d_in[5];
    const float* b_e3  = (const float*)d_in[6];
    const float* w_d3  = (const float*)d_in[7];
    const float* b_d3  = (const float*)d_in[8];
    const float* w_d2  = (const float*)d_in[9];
    const float* b_d2  = (const float*)d_in[10];
    const float* w_d1  = (const float*)d_in[11];
    const float* b_d1  = (const float*)d_in[12];
    const float* w_sk2 = (const float*)d_in[13];
    const float* w_sk1 = (const float*)d_in[14];
    const float* w_fl  = (const float*)d_in[15];
    const float* b_fl  = (const float*)d_in[16];

    char* ws = (char*)d_ws;
    float* me1 = (float*)(ws + O_ME1);
    float* me2 = (float*)(ws + O_ME2);
    float* me3 = (float*)(ws + O_ME3);
    float* md3 = (float*)(ws + O_MD3);
    float* md2 = (float*)(ws + O_MD2);
    float* md1 = (float*)(ws + O_MD1);
    float* mn1 = (float*)(ws + O_MN1);
    float* mn2 = (float*)(ws + O_MN2);
    unsigned char* s1p = (unsigned char*)(ws + O_S1P);
    unsigned char* s2p = (unsigned char*)(ws + O_S2P);
    unsigned char* s3p = (unsigned char*)(ws + O_S3P);
    float* d3fp = (float*)(ws + O_D3FP);
    float* d2fp = (float*)(ws + O_D2FP);
    unsigned char* d1u = (unsigned char*)(ws + O_D1U);   // aliases s1p..d3fp (t=9 only)
    float* eff3 = (float*)(ws + O_EFF3);
    float* eff2 = (float*)(ws + O_EFF2);
    float* eff1 = (float*)(ws + O_EFF1);
    float* wTe1 = (float*)(ws + O_WTE1);
    float* wTe2 = (float*)(ws + O_WTE2);
    float* wTe3 = (float*)(ws + O_WTE3);
    float* wTfl = (float*)(ws + O_WTFL);
    float* wsk2 = (float*)(ws + O_WSK2);
    float* wsk1 = (float*)(ws + O_WSK1);

    // zero membranes / means / all padded planes (pads must stay 0)
    hipMemsetAsync(d_ws, 0, ZERO_BYTES, stream);

    // prepass
    k_transpose_w<32, 2, 5><<<(1600 + 255) / 256, 256, 0, stream>>>(w_e1, wTe1);
    k_transpose_w<64, 32, 3><<<(18432 + 255) / 256, 256, 0, stream>>>(w_e2, wTe2);
    k_transpose_w<128, 64, 3><<<(73728 + 255) / 256, 256, 0, stream>>>(w_e3, wTe3);
    k_transpose_w<2, 32, 3><<<(576 + 255) / 256, 256, 0, stream>>>(w_fl, wTfl);
    k_transpose_w<64, 64, 1><<<(4096 + 255) / 256, 256, 0, stream>>>(w_sk2, wsk2);
    k_transpose_w<32, 32, 1><<<(1024 + 255) / 256, 256, 0, stream>>>(w_sk1, wsk1);
    k_eff<64, 128><<<(2 * 64 * 128 + 255) / 256, 256, 0, stream>>>(w_d3, eff3);
    k_eff<32, 64><<<(2 * 32 * 64 + 255) / 256, 256, 0, stream>>>(w_d2, eff2);
    k_eff<32, 32><<<(2 * 32 * 32 + 255) / 256, 256, 0, stream>>>(w_d1, eff1);

    for (int t = 0; t < TSTEPS; ++t) {
        float inv = 1.0f / (float)(t + 1);
        // e1 -> s1p (padded u8)
        k_e1<16><<<dim3(8, 8, NB * 2), 256, 0, stream>>>(x, wTe1, b_e1, me1, mn1, s1p, t, inv);
        // e2: s1p -> s2p, 1024 blocks
        k_enc2<32, 64, 64, 8, true, 132, 66, 68><<<dim3(1, 16, NB * 8), 256, 0, stream>>>(
            s1p, wTe2, b_e2, me2, mn2, s2p, inv);
        // e3: s2p -> s3p, 512 blocks
        k_enc2<64, 128, 32, 8, false, 68, 34, 36><<<dim3(1, 4, NB * 16), 256, 0, stream>>>(
            s2p, wTe3, b_e3, me3, (float*)nullptr, s3p, 0.f);
        // d3: s3p -> d3fp (padded float), 512 blocks
        k_dec3<<<dim3(1, 2, NB * 2 * 16), 256, 0, stream>>>(
            s3p, eff3, b_d3, md3, mn2, wsk2, d3fp);
        // d2: d3fp -> d2fp (padded float), 1024 blocks
        k_decf<64, 32, 64, true, false, 68, 130, 132><<<dim3(1, 8, NB * 2 * 8), 256, 0, stream>>>(
            d3fp, eff2, b_d2, md2, mn1, wsk1, d2fp, 1);
        // d1: d2fp -> d1u (u8, t=9 only), 4096 blocks
        k_decf<32, 32, 128, false, true, 132, 0, 0><<<dim3(2, 16, NB * 2 * 8), 256, 0, stream>>>(
            d2fp, eff1, b_d1, md1, (const float*)nullptr, (const float*)nullptr, d1u,
            (t == TSTEPS - 1) ? 1 : 0);
    }
    k_flow<<<dim3(16, 16, NB), 256, 0, stream>>>(d1u, wTfl, b_fl, (float*)d_out);
}

// Round 12
// 2740.067 us; speedup vs baseline: 2.2234x; 1.1565x over previous
//
#include <hip/hip_runtime.h>

// =====================  problem constants  =====================
constexpr int NB = 8;        // batch
constexpr int TSTEPS = 10;   // timesteps

// =====================  workspace layout (bytes)  =====================
constexpr size_t SZ_ME1 = (size_t)NB*32*128*128*4;
constexpr size_t SZ_ME2 = (size_t)NB*64*64*64*4;
constexpr size_t SZ_ME3 = (size_t)NB*128*32*32*4;
constexpr size_t SZ_MD3 = SZ_ME2;
constexpr size_t SZ_MD2 = SZ_ME1;
constexpr size_t SZ_MD1 = (size_t)NB*32*256*256*4;
constexpr size_t SZ_MN1 = SZ_ME1;
constexpr size_t SZ_MN2 = SZ_ME2;
// zero-padded activation planes (pads must stay 0; interiors rewritten each step)
constexpr size_t SZ_S1P  = (size_t)NB*32*130*132;      // e1 spikes u8, interior (+1,+1)
constexpr size_t SZ_S2P  = (size_t)NB*64*66*68;        // e2 spikes u8, interior (+1,+1)
constexpr size_t SZ_S3P  = (size_t)NB*128*34*36;       // e3 spikes u8, interior (+1,+1)
constexpr size_t SZ_D3FP = (size_t)NB*64*66*68*4;      // d3 out float, interior (+1,+2)
constexpr size_t SZ_D2FP = (size_t)NB*32*130*132*4;    // d2 out float, interior (+1,+2)

constexpr size_t O_ME1 = 0;
constexpr size_t O_ME2 = O_ME1 + SZ_ME1;
constexpr size_t O_ME3 = O_ME2 + SZ_ME2;
constexpr size_t O_MD3 = O_ME3 + SZ_ME3;
constexpr size_t O_MD2 = O_MD3 + SZ_MD3;
constexpr size_t O_MD1 = O_MD2 + SZ_MD2;
constexpr size_t O_MN1 = O_MD1 + SZ_MD1;
constexpr size_t O_MN2 = O_MN1 + SZ_MN1;
constexpr size_t O_S1P  = O_MN2 + SZ_MN2;
constexpr size_t O_S2P  = O_S1P + SZ_S1P;
constexpr size_t O_S3P  = O_S2P + SZ_S2P;
constexpr size_t O_D3FP = O_S3P + SZ_S3P;
constexpr size_t O_D2FP = O_D3FP + SZ_D3FP;
constexpr size_t ZERO_BYTES = O_D2FP + SZ_D2FP;        // ~181.5 MB zeroed each launch

// d1u (u8, 16.78MB) ALIASES s1p..d3fp (17.14MB): written only at t=9, after all
// readers of s1p/s2p/s3p/d3fp for that step have completed (stream-ordered).
constexpr size_t O_D1U = O_S1P;
static_assert(SZ_S1P + SZ_S2P + SZ_S3P + SZ_D3FP >= (size_t)NB*32*256*256, "alias fits");

constexpr size_t O_EFF3 = ZERO_BYTES;                  // eff tables (float)
constexpr size_t O_EFF2 = O_EFF3 + (size_t)2*64*128*8*4;
constexpr size_t O_EFF1 = O_EFF2 + (size_t)2*32*64*8*4;
constexpr size_t O_WTE1 = O_EFF1 + (size_t)2*32*32*8*4; // transposed weights
constexpr size_t O_WTE2 = O_WTE1 + (size_t)2*5*5*32*4;
constexpr size_t O_WTE3 = O_WTE2 + (size_t)32*3*3*64*4;
constexpr size_t O_WTFL = O_WTE3 + (size_t)64*3*3*128*4;
constexpr size_t O_WSK2 = O_WTFL + (size_t)32*3*3*2*4;
constexpr size_t O_WSK1 = O_WSK2 + (size_t)64*64*4;
// end: ~182.3 MiB (< 197 MiB proven-good)

// =====================  prepass kernels  =====================
template<int OC, int IC, int K>
__global__ void k_transpose_w(const float* __restrict__ w, float* __restrict__ wT) {
    int i = blockIdx.x * 256 + threadIdx.x;
    constexpr int total = OC * IC * K * K;
    if (i >= total) return;
    int oc = i % OC; int r = i / OC;
    int kx = r % K;  r /= K;
    int ky = r % K;  r /= K;
    int ci = r;
    wT[i] = w[((oc * IC + ci) * K + ky) * K + kx];
}

// eff[((py*OC+oc)*IC+ci)*8 + (px*4 + di*2 + dj)]
template<int OC, int IC>
__global__ void k_eff(const float* __restrict__ w, float* __restrict__ eff) {
    int i = blockIdx.x * 256 + threadIdx.x;
    constexpr int total = 2 * OC * IC;
    if (i >= total) return;
    int ci = i % IC; int r = i / IC;
    int oc = r % OC; int py = r / OC;
    const float* wp = w + ((size_t)oc * IC + ci) * 9;
    float w00=wp[0],w01=wp[1],w02=wp[2],w10=wp[3],w11=wp[4],w12=wp[5],w20=wp[6],w21=wp[7],w22=wp[8];
    float r0c0,r0c1,r0c2,r1c0,r1c1,r1c2;
    if (py == 0) { r0c0=w00;     r0c1=w01;     r0c2=w02;     r1c0=w10+w20; r1c1=w11+w21; r1c2=w12+w22; }
    else         { r0c0=w00+w10; r0c1=w01+w11; r0c2=w02+w12; r1c0=w20;     r1c1=w21;     r1c2=w22;     }
    float* e = eff + (size_t)i * 8;
    e[0] = r0c0;        e[1] = r0c1 + r0c2;   // px=0
    e[2] = r1c0;        e[3] = r1c1 + r1c2;
    e[4] = r0c0 + r0c1; e[5] = r0c2;          // px=1
    e[6] = r1c0 + r1c1; e[7] = r1c2;
}

// =====================  e1: 5x5 s2 p2 conv + LIF (fp32 input, LDS tile)  ============
template<int OCCH>
__global__ __launch_bounds__(256) void k_e1(
    const float* __restrict__ x, const float* __restrict__ wT, const float* __restrict__ b,
    float* __restrict__ me1, float* __restrict__ mn1, unsigned char* __restrict__ s1p,
    int t, float inv)
{
    __shared__ float tile[2 * 35 * 36];
    const int tx = threadIdx.x & 15, ty = threadIdx.x >> 4;
    constexpr int nchunks = 32 / OCCH;
    int zi = blockIdx.z;
    const int ocb = (zi % nchunks) * OCCH;
    const int n = zi / nchunks;
    const int oy0 = blockIdx.y * 16, ox0 = blockIdx.x * 16;
    const int iy0 = oy0 * 2 - 2, ix0 = ox0 * 2 - 2;

    for (int e = threadIdx.x; e < 2 * 35 * 35; e += 256) {
        int c = e % 35; int r = (e / 35) % 35; int ci = e / (35 * 35);
        int gy = iy0 + r, gx = ix0 + c;
        float v = 0.f;
        if (gy >= 0 && gy < 256 && gx >= 0 && gx < 256)
            v = x[((((size_t)n * TSTEPS + t) * 2 + ci) * 256 + gy) * 256 + gx];
        tile[(ci * 35 + r) * 36 + c] = v;
    }
    __syncthreads();

    float acc[OCCH];
#pragma unroll
    for (int oc = 0; oc < OCCH; ++oc) acc[oc] = b[ocb + oc];
#pragma unroll
    for (int ci = 0; ci < 2; ++ci)
#pragma unroll
        for (int ky = 0; ky < 5; ++ky)
#pragma unroll
            for (int kx = 0; kx < 5; ++kx) {
                float v = tile[(ci * 35 + ty * 2 + ky) * 36 + tx * 2 + kx];
                const float* wp = wT + ((ci * 5 + ky) * 5 + kx) * 32 + ocb;
#pragma unroll
                for (int oc = 0; oc < OCCH; ++oc) acc[oc] = fmaf(v, wp[oc], acc[oc]);
            }

    const int oy = oy0 + ty, ox = ox0 + tx;
#pragma unroll
    for (int oc = 0; oc < OCCH; ++oc) {
        size_t idx = (((size_t)n * 32 + ocb + oc) * 128 + oy) * 128 + ox;
        float mo = me1[idx];
        float m  = mo + (acc[oc] - mo) * 0.5f;
        float s  = (m > 1.0f) ? 1.0f : 0.0f;
        me1[idx] = m - s;
        float mn = mn1[idx];
        mn1[idx] = mn + (s - mn) * inv;
        s1p[((size_t)(n * 32 + ocb + oc) * 130 + 1 + oy) * 132 + 1 + ox] = (unsigned char)s;
    }
}

// =====================  e2/e3: stride-2 3x3 conv + LIF, direct-global  ===============
template<int IC, int OC, int OUT, int OCCH, bool MEAN, int PIN_W, int POUT_H, int POUT_W>
__global__ __launch_bounds__(256) void k_enc2(
    const unsigned char* __restrict__ sinp, const float* __restrict__ wT, const float* __restrict__ b,
    float* __restrict__ mem, float* __restrict__ mn, unsigned char* __restrict__ soutp, float inv)
{
    constexpr int PIN_H = 2 * OUT + 2;
    constexpr int PIN_PLANE = PIN_H * PIN_W;
    constexpr int RPB = 256 / OUT;              // rows per block
    constexpr int nchunks = OC / OCCH;
    const int tx = (int)threadIdx.x % OUT;
    const int ty = (int)threadIdx.x / OUT;
    int zi = blockIdx.z;
    const int ocb = (zi % nchunks) * OCCH;
    const int n = zi / nchunks;
    const int oy = blockIdx.y * RPB + ty;
    const int ox = tx;

    const unsigned char* sp = sinp + (size_t)n * IC * PIN_PLANE + (size_t)(2 * oy) * PIN_W + 2 * ox;
    const float* wbase = wT + ocb;

    float acc[OCCH];
#pragma unroll
    for (int oc = 0; oc < OCCH; ++oc) acc[oc] = b[ocb + oc];

#pragma unroll 2
    for (int ci = 0; ci < IC; ++ci) {
        const unsigned char* p = sp + (size_t)ci * PIN_PLANE;
        float v00 = (float)p[0],          v01 = (float)p[1],          v02 = (float)p[2];
        float v10 = (float)p[PIN_W],      v11 = (float)p[PIN_W + 1],  v12 = (float)p[PIN_W + 2];
        float v20 = (float)p[2 * PIN_W],  v21 = (float)p[2 * PIN_W + 1], v22 = (float)p[2 * PIN_W + 2];
        const float* w0 = wbase + (size_t)(ci * 9 + 0) * OC;
        const float* w1 = wbase + (size_t)(ci * 9 + 1) * OC;
        const float* w2 = wbase + (size_t)(ci * 9 + 2) * OC;
        const float* w3 = wbase + (size_t)(ci * 9 + 3) * OC;
        const float* w4 = wbase + (size_t)(ci * 9 + 4) * OC;
        const float* w5 = wbase + (size_t)(ci * 9 + 5) * OC;
        const float* w6 = wbase + (size_t)(ci * 9 + 6) * OC;
        const float* w7 = wbase + (size_t)(ci * 9 + 7) * OC;
        const float* w8 = wbase + (size_t)(ci * 9 + 8) * OC;
#pragma unroll
        for (int oc = 0; oc < OCCH; ++oc) {
            float a = acc[oc];
            a = fmaf(v00, w0[oc], a); a = fmaf(v01, w1[oc], a); a = fmaf(v02, w2[oc], a);
            a = fmaf(v10, w3[oc], a); a = fmaf(v11, w4[oc], a); a = fmaf(v12, w5[oc], a);
            a = fmaf(v20, w6[oc], a); a = fmaf(v21, w7[oc], a); a = fmaf(v22, w8[oc], a);
            acc[oc] = a;
        }
    }

#pragma unroll
    for (int oc = 0; oc < OCCH; ++oc) {
        size_t idx = (((size_t)n * OC + ocb + oc) * OUT + oy) * OUT + ox;
        float mo = mem[idx];
        float m  = mo + (acc[oc] - mo) * 0.5f;
        float s  = (m > 1.0f) ? 1.0f : 0.0f;
        mem[idx] = m - s;
        if constexpr (MEAN) { float mv = mn[idx]; mn[idx] = mv + (s - mv) * inv; }
        soutp[((size_t)(n * OC + ocb + oc) * POUT_H + 1 + oy) * POUT_W + 1 + ox] = (unsigned char)s;
    }
}

// =====================  d3: direct-global decoder (u8 in, padded-float out)  =========
__global__ __launch_bounds__(256) void k_dec3(
    const unsigned char* __restrict__ s3p, const float* __restrict__ eff,
    const float* __restrict__ b, float* __restrict__ mem,
    const float* __restrict__ mn2, const float* __restrict__ wskT,
    float* __restrict__ outp)
{
    constexpr int IC = 128, OC = 64, OCCH = 4;
    constexpr int PW = 36, PLANE = 34 * 36;
    const int tx = threadIdx.x & 31;          // col-pair j
    const int ty = threadIdx.x >> 5;          // 0..7
    int zi = blockIdx.z;
    const int ocb = (zi & 15) * OCCH; zi >>= 4;
    const int py = zi & 1;
    const int n  = zi >> 1;
    const int i0 = blockIdx.y * 16 + ty * 2;  // plane rows i0, i0+1

    const unsigned char* sp = s3p + (size_t)n * IC * PLANE + (size_t)(i0 + py) * PW + tx;
    const float* ep = eff + ((size_t)py * OC + ocb) * IC * 8;

    float accA0[OCCH] = {0.f,0.f,0.f,0.f}, accB0[OCCH] = {0.f,0.f,0.f,0.f};
    float accA1[OCCH] = {0.f,0.f,0.f,0.f}, accB1[OCCH] = {0.f,0.f,0.f,0.f};

#pragma unroll 2
    for (int ci = 0; ci < IC; ++ci) {
        const unsigned char* p = sp + (size_t)ci * PLANE;
        float v00 = (float)p[0],      v01 = (float)p[1],      v02 = (float)p[2];
        float v10 = (float)p[PW],     v11 = (float)p[PW+1],   v12 = (float)p[PW+2];
        float v20 = (float)p[2*PW],   v21 = (float)p[2*PW+1], v22 = (float)p[2*PW+2];
#pragma unroll
        for (int oc = 0; oc < OCCH; ++oc) {
            const float* e8 = ep + ((size_t)oc * IC + ci) * 8;
            float e0=e8[0], e1=e8[1], e2=e8[2], e3=e8[3];
            float e4=e8[4], e5=e8[5], e6=e8[6], e7=e8[7];
            accA0[oc] = fmaf(v00,e0, fmaf(v01,e1, fmaf(v10,e2, fmaf(v11,e3, accA0[oc]))));
            accB0[oc] = fmaf(v01,e4, fmaf(v02,e5, fmaf(v11,e6, fmaf(v12,e7, accB0[oc]))));
            accA1[oc] = fmaf(v10,e0, fmaf(v11,e1, fmaf(v20,e2, fmaf(v21,e3, accA1[oc]))));
            accB1[oc] = fmaf(v11,e4, fmaf(v12,e5, fmaf(v21,e6, fmaf(v22,e7, accB1[oc]))));
        }
    }

    const int oy0 = 2 * i0 + py;
    const int ox0 = 2 * tx;

#pragma unroll
    for (int oc = 0; oc < OCCH; ++oc) {
        float bb = b[ocb + oc];
        size_t ia = (((size_t)n * OC + ocb + oc) * 64 + oy0) * 64 + ox0;
        size_t ib = ia + 2 * 64;
        float2 m0 = *(const float2*)(mem + ia);
        float2 m1 = *(const float2*)(mem + ib);
        float cA0 = accA0[oc] + bb, cB0 = accB0[oc] + bb;
        float cA1 = accA1[oc] + bb, cB1 = accB1[oc] + bb;
        float mA0 = m0.x + (cA0 - m0.x) * 0.5f;
        float mB0 = m0.y + (cB0 - m0.y) * 0.5f;
        float mA1 = m1.x + (cA1 - m1.x) * 0.5f;
        float mB1 = m1.y + (cB1 - m1.y) * 0.5f;
        float sA0 = (mA0 > 1.f) ? 1.f : 0.f;
        float sB0 = (mB0 > 1.f) ? 1.f : 0.f;
        float sA1 = (mA1 > 1.f) ? 1.f : 0.f;
        float sB1 = (mB1 > 1.f) ? 1.f : 0.f;
        *(float2*)(mem + ia) = make_float2(mA0 - sA0, mB0 - sB0);
        *(float2*)(mem + ib) = make_float2(mA1 - sA1, mB1 - sB1);
        accA0[oc] = sA0; accB0[oc] = sB0; accA1[oc] = sA1; accB1[oc] = sB1;
    }

#pragma unroll 4
    for (int ci = 0; ci < OC; ++ci) {
        const float* wp = wskT + ci * OC + ocb;
        size_t sbase = (((size_t)n * OC + ci) * 64 + oy0) * 64 + ox0;
        float2 v0 = *(const float2*)(mn2 + sbase);
        float2 v1 = *(const float2*)(mn2 + sbase + 2 * 64);
#pragma unroll
        for (int oc = 0; oc < OCCH; ++oc) {
            accA0[oc] = fmaf(v0.x, wp[oc], accA0[oc]);
            accB0[oc] = fmaf(v0.y, wp[oc], accB0[oc]);
            accA1[oc] = fmaf(v1.x, wp[oc], accA1[oc]);
            accB1[oc] = fmaf(v1.y, wp[oc], accB1[oc]);
        }
    }

    // store to padded d3fp [66][68], interior (+1,+2); ox0 even -> 8B aligned
#pragma unroll
    for (int oc = 0; oc < OCCH; ++oc) {
        size_t ob = ((size_t)(n * OC + ocb + oc) * 66 + (oy0 + 1)) * 68 + (ox0 + 2);
        *(float2*)(outp + ob)          = make_float2(accA0[oc], accB0[oc]);
        *(float2*)(outp + ob + 2 * 68) = make_float2(accA1[oc], accB1[oc]);
    }
}

// =====================  d2/d1: direct-global decoder (padded-float in)  ==============
// OCCH=8: 128 FMA per 9 input loads per ci (latency-hiding via acc-block depth).
template<int IC, int OC, int SRC, int OCCH, bool SKIP, bool OUTU8, int PIN_W, int POUT_H, int POUT_W>
__global__ __launch_bounds__(256) void k_decf(
    const float* __restrict__ sinp, const float* __restrict__ eff, const float* __restrict__ b,
    float* __restrict__ mem, const float* __restrict__ mnsk, const float* __restrict__ wskT,
    void* __restrict__ outv, int store_out)
{
    constexpr int OUT = SRC * 2;
    constexpr int PIN_H = SRC + 2;
    constexpr int PIN_PLANE = PIN_H * PIN_W;
    constexpr int nchunks = OC / OCCH;
    const int tx = (int)threadIdx.x & 63;
    const int ty = (int)threadIdx.x >> 6;      // 0..3
    const int J = blockIdx.x * 64 + tx;        // col-pair
    int zi = blockIdx.z;
    const int ocb = (zi % nchunks) * OCCH; zi /= nchunks;
    const int py = zi & 1;
    const int n  = zi >> 1;
    const int i0 = blockIdx.y * 8 + ty * 2;    // plane rows i0, i0+1

    const float* sp = sinp + (size_t)n * IC * PIN_PLANE + (size_t)(i0 + py) * PIN_W + (J + 1);
    const float* ep = eff + ((size_t)py * OC + ocb) * IC * 8;

    float accA0[OCCH], accB0[OCCH], accA1[OCCH], accB1[OCCH];
#pragma unroll
    for (int oc = 0; oc < OCCH; ++oc) { accA0[oc]=0.f; accB0[oc]=0.f; accA1[oc]=0.f; accB1[oc]=0.f; }

#pragma unroll 2
    for (int ci = 0; ci < IC; ++ci) {
        const float* p = sp + (size_t)ci * PIN_PLANE;
        float v00 = p[0],          v01 = p[1],          v02 = p[2];
        float v10 = p[PIN_W],      v11 = p[PIN_W + 1],  v12 = p[PIN_W + 2];
        float v20 = p[2 * PIN_W],  v21 = p[2 * PIN_W + 1], v22 = p[2 * PIN_W + 2];
#pragma unroll
        for (int oc = 0; oc < OCCH; ++oc) {
            const float* e8 = ep + ((size_t)oc * IC + ci) * 8;
            float e0=e8[0], e1=e8[1], e2=e8[2], e3=e8[3];
            float e4=e8[4], e5=e8[5], e6=e8[6], e7=e8[7];
            accA0[oc] = fmaf(v00,e0, fmaf(v01,e1, fmaf(v10,e2, fmaf(v11,e3, accA0[oc]))));
            accB0[oc] = fmaf(v01,e4, fmaf(v02,e5, fmaf(v11,e6, fmaf(v12,e7, accB0[oc]))));
            accA1[oc] = fmaf(v10,e0, fmaf(v11,e1, fmaf(v20,e2, fmaf(v21,e3, accA1[oc]))));
            accB1[oc] = fmaf(v11,e4, fmaf(v12,e5, fmaf(v21,e6, fmaf(v22,e7, accB1[oc]))));
        }
    }

    const int oy0 = 2 * i0 + py;
    const int ox0 = 2 * J;

#pragma unroll
    for (int oc = 0; oc < OCCH; ++oc) {
        float bb = b[ocb + oc];
        size_t ia = (((size_t)n * OC + ocb + oc) * OUT + oy0) * OUT + ox0;
        size_t ib = ia + 2 * OUT;
        float2 m0 = *(const float2*)(mem + ia);
        float2 m1 = *(const float2*)(mem + ib);
        float cA0 = accA0[oc] + bb, cB0 = accB0[oc] + bb;
        float cA1 = accA1[oc] + bb, cB1 = accB1[oc] + bb;
        float mA0 = m0.x + (cA0 - m0.x) * 0.5f;
        float mB0 = m0.y + (cB0 - m0.y) * 0.5f;
        float mA1 = m1.x + (cA1 - m1.x) * 0.5f;
        float mB1 = m1.y + (cB1 - m1.y) * 0.5f;
        float sA0 = (mA0 > 1.f) ? 1.f : 0.f;
        float sB0 = (mB0 > 1.f) ? 1.f : 0.f;
        float sA1 = (mA1 > 1.f) ? 1.f : 0.f;
        float sB1 = (mB1 > 1.f) ? 1.f : 0.f;
        *(float2*)(mem + ia) = make_float2(mA0 - sA0, mB0 - sB0);
        *(float2*)(mem + ib) = make_float2(mA1 - sA1, mB1 - sB1);
        accA0[oc] = sA0; accB0[oc] = sB0; accA1[oc] = sA1; accB1[oc] = sB1;
    }

    if constexpr (SKIP) {
#pragma unroll 4
        for (int ci = 0; ci < OC; ++ci) {
            const float* wp = wskT + ci * OC + ocb;
            size_t sbase = (((size_t)n * OC + ci) * OUT + oy0) * OUT + ox0;
            float2 v0 = *(const float2*)(mnsk + sbase);
            float2 v1 = *(const float2*)(mnsk + sbase + 2 * OUT);
#pragma unroll
            for (int oc = 0; oc < OCCH; ++oc) {
                accA0[oc] = fmaf(v0.x, wp[oc], accA0[oc]);
                accB0[oc] = fmaf(v0.y, wp[oc], accB0[oc]);
                accA1[oc] = fmaf(v1.x, wp[oc], accA1[oc]);
                accB1[oc] = fmaf(v1.y, wp[oc], accB1[oc]);
            }
        }
    }

    if constexpr (OUTU8) {
        if (store_out) {
            unsigned char* o8 = (unsigned char*)outv;
#pragma unroll
            for (int oc = 0; oc < OCCH; ++oc) {
                size_t ob = (((size_t)n * OC + ocb + oc) * OUT + oy0) * OUT + ox0;
                o8[ob]               = (unsigned char)accA0[oc];
                o8[ob + 1]           = (unsigned char)accB0[oc];
                o8[ob + 2 * OUT]     = (unsigned char)accA1[oc];
                o8[ob + 2 * OUT + 1] = (unsigned char)accB1[oc];
            }
        }
    } else {
        float* of = (float*)outv;
#pragma unroll
        for (int oc = 0; oc < OCCH; ++oc) {
            size_t ob = ((size_t)(n * OC + ocb + oc) * POUT_H + (oy0 + 1)) * POUT_W + (ox0 + 2);
            *(float2*)(of + ob)              = make_float2(accA0[oc], accB0[oc]);
            *(float2*)(of + ob + 2 * POUT_W) = make_float2(accA1[oc], accB1[oc]);
        }
    }
}

// =====================  final flow conv (3x3 s1 p1, 32->2, *16)  =====================
__global__ __launch_bounds__(256) void k_flow(
    const unsigned char* __restrict__ d1, const float* __restrict__ wT, const float* __restrict__ b,
    float* __restrict__ out)
{
    constexpr int HW = 256;
    __shared__ unsigned char tile[32 * 18 * 19];
    const int tx = threadIdx.x & 15, ty = threadIdx.x >> 4;
    const int n = blockIdx.z;
    const int oy0 = blockIdx.y * 16, ox0 = blockIdx.x * 16;

    for (int e = threadIdx.x; e < 32 * 18 * 18; e += 256) {
        int c = e % 18; int r = (e / 18) % 18; int ci = e / (18 * 18);
        int gy = oy0 - 1 + r, gx = ox0 - 1 + c;
        unsigned char v = 0;
        if (gy >= 0 && gy < HW && gx >= 0 && gx < HW)
            v = d1[(((size_t)n * 32 + ci) * HW + gy) * HW + gx];
        tile[(ci * 18 + r) * 19 + c] = v;
    }
    __syncthreads();

    float a0 = b[0], a1 = b[1];
#pragma unroll 2
    for (int ci = 0; ci < 32; ++ci)
#pragma unroll
        for (int ky = 0; ky < 3; ++ky)
#pragma unroll
            for (int kx = 0; kx < 3; ++kx) {
                float v = (float)tile[(ci * 18 + ty + ky) * 19 + tx + kx];
                const float* wp = wT + ((ci * 3 + ky) * 3 + kx) * 2;
                a0 = fmaf(v, wp[0], a0);
                a1 = fmaf(v, wp[1], a1);
            }

    const int oy = oy0 + ty, ox = ox0 + tx;
    out[(((size_t)n * 2 + 0) * HW + oy) * HW + ox] = a0 * 16.f;
    out[(((size_t)n * 2 + 1) * HW + oy) * HW + ox] = a1 * 16.f;
}

// =====================  launch  =====================
extern "C" void kernel_launch(void* const* d_in, const int* in_sizes, int n_in,
                              void* d_out, int out_size, void* d_ws, size_t ws_size,
                              hipStream_t stream)
{
    const float* x     = (const float*)d_in[0];
    const float* w_e1  = (const float*)d_in[1];
    const float* b_e1  = (const float*)d_in[2];
    const float* w_e2  = (const float*)d_in[3];
    const float* b_e2  = (const float*)d_in[4];
    const float* w_e3  = (const float*)d_in[5];
    const float* b_e3  = (const float*)d_in[6];
    const float* w_d3  = (const float*)d_in[7];
    const float* b_d3  = (const float*)d_in[8];
    const float* w_d2  = (const float*)d_in[9];
    const float* b_d2  = (const float*)d_in[10];
    const float* w_d1  = (const float*)d_in[11];
    const float* b_d1  = (const float*)d_in[12];
    const float* w_sk2 = (const float*)d_in[13];
    const float* w_sk1 = (const float*)d_in[14];
    const float* w_fl  = (const float*)d_in[15];
    const float* b_fl  = (const float*)d_in[16];

    char* ws = (char*)d_ws;
    float* me1 = (float*)(ws + O_ME1);
    float* me2 = (float*)(ws + O_ME2);
    float* me3 = (float*)(ws + O_ME3);
    float* md3 = (float*)(ws + O_MD3);
    float* md2 = (float*)(ws + O_MD2);
    float* md1 = (float*)(ws + O_MD1);
    float* mn1 = (float*)(ws + O_MN1);
    float* mn2 = (float*)(ws + O_MN2);
    unsigned char* s1p = (unsigned char*)(ws + O_S1P);
    unsigned char* s2p = (unsigned char*)(ws + O_S2P);
    unsigned char* s3p = (unsigned char*)(ws + O_S3P);
    float* d3fp = (float*)(ws + O_D3FP);
    float* d2fp = (float*)(ws + O_D2FP);
    unsigned char* d1u = (unsigned char*)(ws + O_D1U);   // aliases s1p..d3fp (t=9 only)
    float* eff3 = (float*)(ws + O_EFF3);
    float* eff2 = (float*)(ws + O_EFF2);
    float* eff1 = (float*)(ws + O_EFF1);
    float* wTe1 = (float*)(ws + O_WTE1);
    float* wTe2 = (float*)(ws + O_WTE2);
    float* wTe3 = (float*)(ws + O_WTE3);
    float* wTfl = (float*)(ws + O_WTFL);
    float* wsk2 = (float*)(ws + O_WSK2);
    float* wsk1 = (float*)(ws + O_WSK1);

    // zero membranes / means / all padded planes (pads must stay 0)
    hipMemsetAsync(d_ws, 0, ZERO_BYTES, stream);

    // prepass
    k_transpose_w<32, 2, 5><<<(1600 + 255) / 256, 256, 0, stream>>>(w_e1, wTe1);
    k_transpose_w<64, 32, 3><<<(18432 + 255) / 256, 256, 0, stream>>>(w_e2, wTe2);
    k_transpose_w<128, 64, 3><<<(73728 + 255) / 256, 256, 0, stream>>>(w_e3, wTe3);
    k_transpose_w<2, 32, 3><<<(576 + 255) / 256, 256, 0, stream>>>(w_fl, wTfl);
    k_transpose_w<64, 64, 1><<<(4096 + 255) / 256, 256, 0, stream>>>(w_sk2, wsk2);
    k_transpose_w<32, 32, 1><<<(1024 + 255) / 256, 256, 0, stream>>>(w_sk1, wsk1);
    k_eff<64, 128><<<(2 * 64 * 128 + 255) / 256, 256, 0, stream>>>(w_d3, eff3);
    k_eff<32, 64><<<(2 * 32 * 64 + 255) / 256, 256, 0, stream>>>(w_d2, eff2);
    k_eff<32, 32><<<(2 * 32 * 32 + 255) / 256, 256, 0, stream>>>(w_d1, eff1);

    for (int t = 0; t < TSTEPS; ++t) {
        float inv = 1.0f / (float)(t + 1);
        // e1 -> s1p (padded u8)
        k_e1<16><<<dim3(8, 8, NB * 2), 256, 0, stream>>>(x, wTe1, b_e1, me1, mn1, s1p, t, inv);
        // e2: s1p -> s2p, 1024 blocks
        k_enc2<32, 64, 64, 8, true, 132, 66, 68><<<dim3(1, 16, NB * 8), 256, 0, stream>>>(
            s1p, wTe2, b_e2, me2, mn2, s2p, inv);
        // e3: s2p -> s3p, 512 blocks
        k_enc2<64, 128, 32, 8, false, 68, 34, 36><<<dim3(1, 4, NB * 16), 256, 0, stream>>>(
            s2p, wTe3, b_e3, me3, (float*)nullptr, s3p, 0.f);
        // d3: s3p -> d3fp (padded float), 512 blocks
        k_dec3<<<dim3(1, 2, NB * 2 * 16), 256, 0, stream>>>(
            s3p, eff3, b_d3, md3, mn2, wsk2, d3fp);
        // d2: d3fp -> d2fp (padded float), OCCH=8 -> 512 blocks
        k_decf<64, 32, 64, 8, true, false, 68, 130, 132><<<dim3(1, 8, NB * 2 * 4), 256, 0, stream>>>(
            d3fp, eff2, b_d2, md2, mn1, wsk1, d2fp, 1);
        // d1: d2fp -> d1u (u8, t=9 only), OCCH=8 -> 2048 blocks
        k_decf<32, 32, 128, 8, false, true, 132, 0, 0><<<dim3(2, 16, NB * 2 * 4), 256, 0, stream>>>(
            d2fp, eff1, b_d1, md1, (const float*)nullptr, (const float*)nullptr, d1u,
            (t == TSTEPS - 1) ? 1 : 0);
    }
    k_flow<<<dim3(16, 16, NB), 256, 0, stream>>>(d1u, wTfl, b_fl, (float*)d_out);
}

// Round 13
// 2738.869 us; speedup vs baseline: 2.2243x; 1.0004x over previous
//
#include <hip/hip_runtime.h>

// =====================  problem constants  =====================
constexpr int NB = 8;        // batch
constexpr int TSTEPS = 10;   // timesteps

// =====================  workspace layout (bytes)  =====================
constexpr size_t SZ_ME1 = (size_t)NB*32*128*128*4;
constexpr size_t SZ_ME2 = (size_t)NB*64*64*64*4;
constexpr size_t SZ_ME3 = (size_t)NB*128*32*32*4;
constexpr size_t SZ_MD3 = SZ_ME2;
constexpr size_t SZ_MD2 = SZ_ME1;
constexpr size_t SZ_MD1 = (size_t)NB*32*256*256*4;
constexpr size_t SZ_MN1 = SZ_ME1;
constexpr size_t SZ_MN2 = SZ_ME2;
// zero-padded activation planes (pads must stay 0; interiors rewritten each step)
constexpr size_t SZ_S1P  = (size_t)NB*32*130*132;      // e1 spikes u8, interior (+1,+1)
constexpr size_t SZ_S2P  = (size_t)NB*64*66*68;        // e2 spikes u8, interior (+1,+1)
constexpr size_t SZ_S3P  = (size_t)NB*128*34*36;       // e3 spikes u8, interior (+1,+1)
constexpr size_t SZ_D3FP = (size_t)NB*64*66*68*4;      // d3 out float, interior (+1,+2)
constexpr size_t SZ_D2FP = (size_t)NB*32*130*132*4;    // d2 out float, interior (+1,+2)

constexpr size_t O_ME1 = 0;
constexpr size_t O_ME2 = O_ME1 + SZ_ME1;
constexpr size_t O_ME3 = O_ME2 + SZ_ME2;
constexpr size_t O_MD3 = O_ME3 + SZ_ME3;
constexpr size_t O_MD2 = O_MD3 + SZ_MD3;
constexpr size_t O_MD1 = O_MD2 + SZ_MD2;
constexpr size_t O_MN1 = O_MD1 + SZ_MD1;
constexpr size_t O_MN2 = O_MN1 + SZ_MN1;
constexpr size_t O_S1P  = O_MN2 + SZ_MN2;
constexpr size_t O_S2P  = O_S1P + SZ_S1P;
constexpr size_t O_S3P  = O_S2P + SZ_S2P;
constexpr size_t O_D3FP = O_S3P + SZ_S3P;
constexpr size_t O_D2FP = O_D3FP + SZ_D3FP;
constexpr size_t ZERO_BYTES = O_D2FP + SZ_D2FP;        // ~181.5 MB zeroed each launch

// d1u (u8, 16.78MB) ALIASES s1p..d3fp (17.14MB): written only at t=9, after all
// readers of s1p/s2p/s3p/d3fp for that step have completed (stream-ordered).
constexpr size_t O_D1U = O_S1P;
static_assert(SZ_S1P + SZ_S2P + SZ_S3P + SZ_D3FP >= (size_t)NB*32*256*256, "alias fits");

constexpr size_t O_EFF3 = ZERO_BYTES;                  // eff tables (float)
constexpr size_t O_EFF2 = O_EFF3 + (size_t)2*64*128*8*4;
constexpr size_t O_EFF1 = O_EFF2 + (size_t)2*32*64*8*4;
constexpr size_t O_WTE1 = O_EFF1 + (size_t)2*32*32*8*4; // transposed weights
constexpr size_t O_WTE2 = O_WTE1 + (size_t)2*5*5*32*4;
constexpr size_t O_WTE3 = O_WTE2 + (size_t)32*3*3*64*4;
constexpr size_t O_WTFL = O_WTE3 + (size_t)64*3*3*128*4;
constexpr size_t O_WSK2 = O_WTFL + (size_t)32*3*3*2*4;
constexpr size_t O_WSK1 = O_WSK2 + (size_t)64*64*4;
// end: ~182.3 MiB (< 197 MiB proven-good)

// =====================  prepass kernels  =====================
template<int OC, int IC, int K>
__global__ void k_transpose_w(const float* __restrict__ w, float* __restrict__ wT) {
    int i = blockIdx.x * 256 + threadIdx.x;
    constexpr int total = OC * IC * K * K;
    if (i >= total) return;
    int oc = i % OC; int r = i / OC;
    int kx = r % K;  r /= K;
    int ky = r % K;  r /= K;
    int ci = r;
    wT[i] = w[((oc * IC + ci) * K + ky) * K + kx];
}

// eff[((py*OC+oc)*IC+ci)*8 + (px*4 + di*2 + dj)]
template<int OC, int IC>
__global__ void k_eff(const float* __restrict__ w, float* __restrict__ eff) {
    int i = blockIdx.x * 256 + threadIdx.x;
    constexpr int total = 2 * OC * IC;
    if (i >= total) return;
    int ci = i % IC; int r = i / IC;
    int oc = r % OC; int py = r / OC;
    const float* wp = w + ((size_t)oc * IC + ci) * 9;
    float w00=wp[0],w01=wp[1],w02=wp[2],w10=wp[3],w11=wp[4],w12=wp[5],w20=wp[6],w21=wp[7],w22=wp[8];
    float r0c0,r0c1,r0c2,r1c0,r1c1,r1c2;
    if (py == 0) { r0c0=w00;     r0c1=w01;     r0c2=w02;     r1c0=w10+w20; r1c1=w11+w21; r1c2=w12+w22; }
    else         { r0c0=w00+w10; r0c1=w01+w11; r0c2=w02+w12; r1c0=w20;     r1c1=w21;     r1c2=w22;     }
    float* e = eff + (size_t)i * 8;
    e[0] = r0c0;        e[1] = r0c1 + r0c2;   // px=0
    e[2] = r1c0;        e[3] = r1c1 + r1c2;
    e[4] = r0c0 + r0c1; e[5] = r0c2;          // px=1
    e[6] = r1c0 + r1c1; e[7] = r1c2;
}

// =====================  e1: 5x5 s2 p2 conv + LIF (fp32 input, LDS tile)  ============
template<int OCCH>
__global__ __launch_bounds__(256, 4) void k_e1(
    const float* __restrict__ x, const float* __restrict__ wT, const float* __restrict__ b,
    float* __restrict__ me1, float* __restrict__ mn1, unsigned char* __restrict__ s1p,
    int t, float inv)
{
    __shared__ float tile[2 * 35 * 36];
    const int tx = threadIdx.x & 15, ty = threadIdx.x >> 4;
    constexpr int nchunks = 32 / OCCH;
    int zi = blockIdx.z;
    const int ocb = (zi % nchunks) * OCCH;
    const int n = zi / nchunks;
    const int oy0 = blockIdx.y * 16, ox0 = blockIdx.x * 16;
    const int iy0 = oy0 * 2 - 2, ix0 = ox0 * 2 - 2;

    for (int e = threadIdx.x; e < 2 * 35 * 35; e += 256) {
        int c = e % 35; int r = (e / 35) % 35; int ci = e / (35 * 35);
        int gy = iy0 + r, gx = ix0 + c;
        float v = 0.f;
        if (gy >= 0 && gy < 256 && gx >= 0 && gx < 256)
            v = x[((((size_t)n * TSTEPS + t) * 2 + ci) * 256 + gy) * 256 + gx];
        tile[(ci * 35 + r) * 36 + c] = v;
    }
    __syncthreads();

    float acc[OCCH];
#pragma unroll
    for (int oc = 0; oc < OCCH; ++oc) acc[oc] = b[ocb + oc];
#pragma unroll
    for (int ci = 0; ci < 2; ++ci)
#pragma unroll
        for (int ky = 0; ky < 5; ++ky)
#pragma unroll
            for (int kx = 0; kx < 5; ++kx) {
                float v = tile[(ci * 35 + ty * 2 + ky) * 36 + tx * 2 + kx];
                const float* wp = wT + ((ci * 5 + ky) * 5 + kx) * 32 + ocb;
#pragma unroll
                for (int oc = 0; oc < OCCH; ++oc) acc[oc] = fmaf(v, wp[oc], acc[oc]);
            }

    const int oy = oy0 + ty, ox = ox0 + tx;
#pragma unroll
    for (int oc = 0; oc < OCCH; ++oc) {
        size_t idx = (((size_t)n * 32 + ocb + oc) * 128 + oy) * 128 + ox;
        float mo = me1[idx];
        float m  = mo + (acc[oc] - mo) * 0.5f;
        float s  = (m > 1.0f) ? 1.0f : 0.0f;
        me1[idx] = m - s;
        float mn = mn1[idx];
        mn1[idx] = mn + (s - mn) * inv;
        s1p[((size_t)(n * 32 + ocb + oc) * 130 + 1 + oy) * 132 + 1 + ox] = (unsigned char)s;
    }
}

// =====================  e2/e3: stride-2 3x3 conv + LIF, direct-global  ===============
// MINW: min waves/SIMD hint — sized to each launch's blocks/CU so the register
// allocator has headroom to software-pipeline the 9-load window across ci.
template<int IC, int OC, int OUT, int OCCH, bool MEAN, int PIN_W, int POUT_H, int POUT_W, int MINW>
__global__ __launch_bounds__(256, MINW) void k_enc2(
    const unsigned char* __restrict__ sinp, const float* __restrict__ wT, const float* __restrict__ b,
    float* __restrict__ mem, float* __restrict__ mn, unsigned char* __restrict__ soutp, float inv)
{
    constexpr int PIN_H = 2 * OUT + 2;
    constexpr int PIN_PLANE = PIN_H * PIN_W;
    constexpr int RPB = 256 / OUT;              // rows per block
    constexpr int nchunks = OC / OCCH;
    const int tx = (int)threadIdx.x % OUT;
    const int ty = (int)threadIdx.x / OUT;
    int zi = blockIdx.z;
    const int ocb = (zi % nchunks) * OCCH;
    const int n = zi / nchunks;
    const int oy = blockIdx.y * RPB + ty;
    const int ox = tx;

    const unsigned char* sp = sinp + (size_t)n * IC * PIN_PLANE + (size_t)(2 * oy) * PIN_W + 2 * ox;
    const float* wbase = wT + ocb;

    float acc[OCCH];
#pragma unroll
    for (int oc = 0; oc < OCCH; ++oc) acc[oc] = b[ocb + oc];

#pragma unroll 2
    for (int ci = 0; ci < IC; ++ci) {
        const unsigned char* p = sp + (size_t)ci * PIN_PLANE;
        float v00 = (float)p[0],          v01 = (float)p[1],          v02 = (float)p[2];
        float v10 = (float)p[PIN_W],      v11 = (float)p[PIN_W + 1],  v12 = (float)p[PIN_W + 2];
        float v20 = (float)p[2 * PIN_W],  v21 = (float)p[2 * PIN_W + 1], v22 = (float)p[2 * PIN_W + 2];
        const float* w0 = wbase + (size_t)(ci * 9 + 0) * OC;
        const float* w1 = wbase + (size_t)(ci * 9 + 1) * OC;
        const float* w2 = wbase + (size_t)(ci * 9 + 2) * OC;
        const float* w3 = wbase + (size_t)(ci * 9 + 3) * OC;
        const float* w4 = wbase + (size_t)(ci * 9 + 4) * OC;
        const float* w5 = wbase + (size_t)(ci * 9 + 5) * OC;
        const float* w6 = wbase + (size_t)(ci * 9 + 6) * OC;
        const float* w7 = wbase + (size_t)(ci * 9 + 7) * OC;
        const float* w8 = wbase + (size_t)(ci * 9 + 8) * OC;
#pragma unroll
        for (int oc = 0; oc < OCCH; ++oc) {
            float a = acc[oc];
            a = fmaf(v00, w0[oc], a); a = fmaf(v01, w1[oc], a); a = fmaf(v02, w2[oc], a);
            a = fmaf(v10, w3[oc], a); a = fmaf(v11, w4[oc], a); a = fmaf(v12, w5[oc], a);
            a = fmaf(v20, w6[oc], a); a = fmaf(v21, w7[oc], a); a = fmaf(v22, w8[oc], a);
            acc[oc] = a;
        }
    }

#pragma unroll
    for (int oc = 0; oc < OCCH; ++oc) {
        size_t idx = (((size_t)n * OC + ocb + oc) * OUT + oy) * OUT + ox;
        float mo = mem[idx];
        float m  = mo + (acc[oc] - mo) * 0.5f;
        float s  = (m > 1.0f) ? 1.0f : 0.0f;
        mem[idx] = m - s;
        if constexpr (MEAN) { float mv = mn[idx]; mn[idx] = mv + (s - mv) * inv; }
        soutp[((size_t)(n * OC + ocb + oc) * POUT_H + 1 + oy) * POUT_W + 1 + ox] = (unsigned char)s;
    }
}

// =====================  d3: direct-global decoder (u8 in, padded-float out)  =========
__global__ __launch_bounds__(256, 2) void k_dec3(
    const unsigned char* __restrict__ s3p, const float* __restrict__ eff,
    const float* __restrict__ b, float* __restrict__ mem,
    const float* __restrict__ mn2, const float* __restrict__ wskT,
    float* __restrict__ outp)
{
    constexpr int IC = 128, OC = 64, OCCH = 4;
    constexpr int PW = 36, PLANE = 34 * 36;
    const int tx = threadIdx.x & 31;          // col-pair j
    const int ty = threadIdx.x >> 5;          // 0..7
    int zi = blockIdx.z;
    const int ocb = (zi & 15) * OCCH; zi >>= 4;
    const int py = zi & 1;
    const int n  = zi >> 1;
    const int i0 = blockIdx.y * 16 + ty * 2;  // plane rows i0, i0+1

    const unsigned char* sp = s3p + (size_t)n * IC * PLANE + (size_t)(i0 + py) * PW + tx;
    const float* ep = eff + ((size_t)py * OC + ocb) * IC * 8;

    float accA0[OCCH] = {0.f,0.f,0.f,0.f}, accB0[OCCH] = {0.f,0.f,0.f,0.f};
    float accA1[OCCH] = {0.f,0.f,0.f,0.f}, accB1[OCCH] = {0.f,0.f,0.f,0.f};

#pragma unroll 2
    for (int ci = 0; ci < IC; ++ci) {
        const unsigned char* p = sp + (size_t)ci * PLANE;
        float v00 = (float)p[0],      v01 = (float)p[1],      v02 = (float)p[2];
        float v10 = (float)p[PW],     v11 = (float)p[PW+1],   v12 = (float)p[PW+2];
        float v20 = (float)p[2*PW],   v21 = (float)p[2*PW+1], v22 = (float)p[2*PW+2];
#pragma unroll
        for (int oc = 0; oc < OCCH; ++oc) {
            const float* e8 = ep + ((size_t)oc * IC + ci) * 8;
            float e0=e8[0], e1=e8[1], e2=e8[2], e3=e8[3];
            float e4=e8[4], e5=e8[5], e6=e8[6], e7=e8[7];
            accA0[oc] = fmaf(v00,e0, fmaf(v01,e1, fmaf(v10,e2, fmaf(v11,e3, accA0[oc]))));
            accB0[oc] = fmaf(v01,e4, fmaf(v02,e5, fmaf(v11,e6, fmaf(v12,e7, accB0[oc]))));
            accA1[oc] = fmaf(v10,e0, fmaf(v11,e1, fmaf(v20,e2, fmaf(v21,e3, accA1[oc]))));
            accB1[oc] = fmaf(v11,e4, fmaf(v12,e5, fmaf(v21,e6, fmaf(v22,e7, accB1[oc]))));
        }
    }

    const int oy0 = 2 * i0 + py;
    const int ox0 = 2 * tx;

#pragma unroll
    for (int oc = 0; oc < OCCH; ++oc) {
        float bb = b[ocb + oc];
        size_t ia = (((size_t)n * OC + ocb + oc) * 64 + oy0) * 64 + ox0;
        size_t ib = ia + 2 * 64;
        float2 m0 = *(const float2*)(mem + ia);
        float2 m1 = *(const float2*)(mem + ib);
        float cA0 = accA0[oc] + bb, cB0 = accB0[oc] + bb;
        float cA1 = accA1[oc] + bb, cB1 = accB1[oc] + bb;
        float mA0 = m0.x + (cA0 - m0.x) * 0.5f;
        float mB0 = m0.y + (cB0 - m0.y) * 0.5f;
        float mA1 = m1.x + (cA1 - m1.x) * 0.5f;
        float mB1 = m1.y + (cB1 - m1.y) * 0.5f;
        float sA0 = (mA0 > 1.f) ? 1.f : 0.f;
        float sB0 = (mB0 > 1.f) ? 1.f : 0.f;
        float sA1 = (mA1 > 1.f) ? 1.f : 0.f;
        float sB1 = (mB1 > 1.f) ? 1.f : 0.f;
        *(float2*)(mem + ia) = make_float2(mA0 - sA0, mB0 - sB0);
        *(float2*)(mem + ib) = make_float2(mA1 - sA1, mB1 - sB1);
        accA0[oc] = sA0; accB0[oc] = sB0; accA1[oc] = sA1; accB1[oc] = sB1;
    }

#pragma unroll 4
    for (int ci = 0; ci < OC; ++ci) {
        const float* wp = wskT + ci * OC + ocb;
        size_t sbase = (((size_t)n * OC + ci) * 64 + oy0) * 64 + ox0;
        float2 v0 = *(const float2*)(mn2 + sbase);
        float2 v1 = *(const float2*)(mn2 + sbase + 2 * 64);
#pragma unroll
        for (int oc = 0; oc < OCCH; ++oc) {
            accA0[oc] = fmaf(v0.x, wp[oc], accA0[oc]);
            accB0[oc] = fmaf(v0.y, wp[oc], accB0[oc]);
            accA1[oc] = fmaf(v1.x, wp[oc], accA1[oc]);
            accB1[oc] = fmaf(v1.y, wp[oc], accB1[oc]);
        }
    }

    // store to padded d3fp [66][68], interior (+1,+2); ox0 even -> 8B aligned
#pragma unroll
    for (int oc = 0; oc < OCCH; ++oc) {
        size_t ob = ((size_t)(n * OC + ocb + oc) * 66 + (oy0 + 1)) * 68 + (ox0 + 2);
        *(float2*)(outp + ob)          = make_float2(accA0[oc], accB0[oc]);
        *(float2*)(outp + ob + 2 * 68) = make_float2(accA1[oc], accB1[oc]);
    }
}

// =====================  d2/d1: direct-global decoder (padded-float in)  ==============
// OCCH=8: 128 FMA per 9 input loads per ci. MINW gives the register allocator
// headroom to pipeline the window loads across ci iterations.
template<int IC, int OC, int SRC, int OCCH, bool SKIP, bool OUTU8, int PIN_W, int POUT_H, int POUT_W, int MINW>
__global__ __launch_bounds__(256, MINW) void k_decf(
    const float* __restrict__ sinp, const float* __restrict__ eff, const float* __restrict__ b,
    float* __restrict__ mem, const float* __restrict__ mnsk, const float* __restrict__ wskT,
    void* __restrict__ outv, int store_out)
{
    constexpr int OUT = SRC * 2;
    constexpr int PIN_H = SRC + 2;
    constexpr int PIN_PLANE = PIN_H * PIN_W;
    constexpr int nchunks = OC / OCCH;
    const int tx = (int)threadIdx.x & 63;
    const int ty = (int)threadIdx.x >> 6;      // 0..3
    const int J = blockIdx.x * 64 + tx;        // col-pair
    int zi = blockIdx.z;
    const int ocb = (zi % nchunks) * OCCH; zi /= nchunks;
    const int py = zi & 1;
    const int n  = zi >> 1;
    const int i0 = blockIdx.y * 8 + ty * 2;    // plane rows i0, i0+1

    const float* sp = sinp + (size_t)n * IC * PIN_PLANE + (size_t)(i0 + py) * PIN_W + (J + 1);
    const float* ep = eff + ((size_t)py * OC + ocb) * IC * 8;

    float accA0[OCCH], accB0[OCCH], accA1[OCCH], accB1[OCCH];
#pragma unroll
    for (int oc = 0; oc < OCCH; ++oc) { accA0[oc]=0.f; accB0[oc]=0.f; accA1[oc]=0.f; accB1[oc]=0.f; }

#pragma unroll 2
    for (int ci = 0; ci < IC; ++ci) {
        const float* p = sp + (size_t)ci * PIN_PLANE;
        float v00 = p[0],          v01 = p[1],          v02 = p[2];
        float v10 = p[PIN_W],      v11 = p[PIN_W + 1],  v12 = p[PIN_W + 2];
        float v20 = p[2 * PIN_W],  v21 = p[2 * PIN_W + 1], v22 = p[2 * PIN_W + 2];
#pragma unroll
        for (int oc = 0; oc < OCCH; ++oc) {
            const float* e8 = ep + ((size_t)oc * IC + ci) * 8;
            float e0=e8[0], e1=e8[1], e2=e8[2], e3=e8[3];
            float e4=e8[4], e5=e8[5], e6=e8[6], e7=e8[7];
            accA0[oc] = fmaf(v00,e0, fmaf(v01,e1, fmaf(v10,e2, fmaf(v11,e3, accA0[oc]))));
            accB0[oc] = fmaf(v01,e4, fmaf(v02,e5, fmaf(v11,e6, fmaf(v12,e7, accB0[oc]))));
            accA1[oc] = fmaf(v10,e0, fmaf(v11,e1, fmaf(v20,e2, fmaf(v21,e3, accA1[oc]))));
            accB1[oc] = fmaf(v11,e4, fmaf(v12,e5, fmaf(v21,e6, fmaf(v22,e7, accB1[oc]))));
        }
    }

    const int oy0 = 2 * i0 + py;
    const int ox0 = 2 * J;

#pragma unroll
    for (int oc = 0; oc < OCCH; ++oc) {
        float bb = b[ocb + oc];
        size_t ia = (((size_t)n * OC + ocb + oc) * OUT + oy0) * OUT + ox0;
        size_t ib = ia + 2 * OUT;
        float2 m0 = *(const float2*)(mem + ia);
        float2 m1 = *(const float2*)(mem + ib);
        float cA0 = accA0[oc] + bb, cB0 = accB0[oc] + bb;
        float cA1 = accA1[oc] + bb, cB1 = accB1[oc] + bb;
        float mA0 = m0.x + (cA0 - m0.x) * 0.5f;
        float mB0 = m0.y + (cB0 - m0.y) * 0.5f;
        float mA1 = m1.x + (cA1 - m1.x) * 0.5f;
        float mB1 = m1.y + (cB1 - m1.y) * 0.5f;
        float sA0 = (mA0 > 1.f) ? 1.f : 0.f;
        float sB0 = (mB0 > 1.f) ? 1.f : 0.f;
        float sA1 = (mA1 > 1.f) ? 1.f : 0.f;
        float sB1 = (mB1 > 1.f) ? 1.f : 0.f;
        *(float2*)(mem + ia) = make_float2(mA0 - sA0, mB0 - sB0);
        *(float2*)(mem + ib) = make_float2(mA1 - sA1, mB1 - sB1);
        accA0[oc] = sA0; accB0[oc] = sB0; accA1[oc] = sA1; accB1[oc] = sB1;
    }

    if constexpr (SKIP) {
#pragma unroll 4
        for (int ci = 0; ci < OC; ++ci) {
            const float* wp = wskT + ci * OC + ocb;
            size_t sbase = (((size_t)n * OC + ci) * OUT + oy0) * OUT + ox0;
            float2 v0 = *(const float2*)(mnsk + sbase);
            float2 v1 = *(const float2*)(mnsk + sbase + 2 * OUT);
#pragma unroll
            for (int oc = 0; oc < OCCH; ++oc) {
                accA0[oc] = fmaf(v0.x, wp[oc], accA0[oc]);
                accB0[oc] = fmaf(v0.y, wp[oc], accB0[oc]);
                accA1[oc] = fmaf(v1.x, wp[oc], accA1[oc]);
                accB1[oc] = fmaf(v1.y, wp[oc], accB1[oc]);
            }
        }
    }

    if constexpr (OUTU8) {
        if (store_out) {
            unsigned char* o8 = (unsigned char*)outv;
#pragma unroll
            for (int oc = 0; oc < OCCH; ++oc) {
                size_t ob = (((size_t)n * OC + ocb + oc) * OUT + oy0) * OUT + ox0;
                o8[ob]               = (unsigned char)accA0[oc];
                o8[ob + 1]           = (unsigned char)accB0[oc];
                o8[ob + 2 * OUT]     = (unsigned char)accA1[oc];
                o8[ob + 2 * OUT + 1] = (unsigned char)accB1[oc];
            }
        }
    } else {
        float* of = (float*)outv;
#pragma unroll
        for (int oc = 0; oc < OCCH; ++oc) {
            size_t ob = ((size_t)(n * OC + ocb + oc) * POUT_H + (oy0 + 1)) * POUT_W + (ox0 + 2);
            *(float2*)(of + ob)              = make_float2(accA0[oc], accB0[oc]);
            *(float2*)(of + ob + 2 * POUT_W) = make_float2(accA1[oc], accB1[oc]);
        }
    }
}

// =====================  final flow conv (3x3 s1 p1, 32->2, *16)  =====================
__global__ __launch_bounds__(256, 4) void k_flow(
    const unsigned char* __restrict__ d1, const float* __restrict__ wT, const float* __restrict__ b,
    float* __restrict__ out)
{
    constexpr int HW = 256;
    __shared__ unsigned char tile[32 * 18 * 19];
    const int tx = threadIdx.x & 15, ty = threadIdx.x >> 4;
    const int n = blockIdx.z;
    const int oy0 = blockIdx.y * 16, ox0 = blockIdx.x * 16;

    for (int e = threadIdx.x; e < 32 * 18 * 18; e += 256) {
        int c = e % 18; int r = (e / 18) % 18; int ci = e / (18 * 18);
        int gy = oy0 - 1 + r, gx = ox0 - 1 + c;
        unsigned char v = 0;
        if (gy >= 0 && gy < HW && gx >= 0 && gx < HW)
            v = d1[(((size_t)n * 32 + ci) * HW + gy) * HW + gx];
        tile[(ci * 18 + r) * 19 + c] = v;
    }
    __syncthreads();

    float a0 = b[0], a1 = b[1];
#pragma unroll 2
    for (int ci = 0; ci < 32; ++ci)
#pragma unroll
        for (int ky = 0; ky < 3; ++ky)
#pragma unroll
            for (int kx = 0; kx < 3; ++kx) {
                float v = (float)tile[(ci * 18 + ty + ky) * 19 + tx + kx];
                const float* wp = wT + ((ci * 3 + ky) * 3 + kx) * 2;
                a0 = fmaf(v, wp[0], a0);
                a1 = fmaf(v, wp[1], a1);
            }

    const int oy = oy0 + ty, ox = ox0 + tx;
    out[(((size_t)n * 2 + 0) * HW + oy) * HW + ox] = a0 * 16.f;
    out[(((size_t)n * 2 + 1) * HW + oy) * HW + ox] = a1 * 16.f;
}

// =====================  launch  =====================
extern "C" void kernel_launch(void* const* d_in, const int* in_sizes, int n_in,
                              void* d_out, int out_size, void* d_ws, size_t ws_size,
                              hipStream_t stream)
{
    const float* x     = (const float*)d_in[0];
    const float* w_e1  = (const float*)d_in[1];
    const float* b_e1  = (const float*)d_in[2];
    const float* w_e2  = (const float*)d_in[3];
    const float* b_e2  = (const float*)d_in[4];
    const float* w_e3  = (const float*)d_in[5];
    const float* b_e3  = (const float*)d_in[6];
    const float* w_d3  = (const float*)d_in[7];
    const float* b_d3  = (const float*)d_in[8];
    const float* w_d2  = (const float*)d_in[9];
    const float* b_d2  = (const float*)d_in[10];
    const float* w_d1  = (const float*)d_in[11];
    const float* b_d1  = (const float*)d_in[12];
    const float* w_sk2 = (const float*)d_in[13];
    const float* w_sk1 = (const float*)d_in[14];
    const float* w_fl  = (const float*)d_in[15];
    const float* b_fl  = (const float*)d_in[16];

    char* ws = (char*)d_ws;
    float* me1 = (float*)(ws + O_ME1);
    float* me2 = (float*)(ws + O_ME2);
    float* me3 = (float*)(ws + O_ME3);
    float* md3 = (float*)(ws + O_MD3);
    float* md2 = (float*)(ws + O_MD2);
    float* md1 = (float*)(ws + O_MD1);
    float* mn1 = (float*)(ws + O_MN1);
    float* mn2 = (float*)(ws + O_MN2);
    unsigned char* s1p = (unsigned char*)(ws + O_S1P);
    unsigned char* s2p = (unsigned char*)(ws + O_S2P);
    unsigned char* s3p = (unsigned char*)(ws + O_S3P);
    float* d3fp = (float*)(ws + O_D3FP);
    float* d2fp = (float*)(ws + O_D2FP);
    unsigned char* d1u = (unsigned char*)(ws + O_D1U);   // aliases s1p..d3fp (t=9 only)
    float* eff3 = (float*)(ws + O_EFF3);
    float* eff2 = (float*)(ws + O_EFF2);
    float* eff1 = (float*)(ws + O_EFF1);
    float* wTe1 = (float*)(ws + O_WTE1);
    float* wTe2 = (float*)(ws + O_WTE2);
    float* wTe3 = (float*)(ws + O_WTE3);
    float* wTfl = (float*)(ws + O_WTFL);
    float* wsk2 = (float*)(ws + O_WSK2);
    float* wsk1 = (float*)(ws + O_WSK1);

    // zero membranes / means / all padded planes (pads must stay 0)
    hipMemsetAsync(d_ws, 0, ZERO_BYTES, stream);

    // prepass
    k_transpose_w<32, 2, 5><<<(1600 + 255) / 256, 256, 0, stream>>>(w_e1, wTe1);
    k_transpose_w<64, 32, 3><<<(18432 + 255) / 256, 256, 0, stream>>>(w_e2, wTe2);
    k_transpose_w<128, 64, 3><<<(73728 + 255) / 256, 256, 0, stream>>>(w_e3, wTe3);
    k_transpose_w<2, 32, 3><<<(576 + 255) / 256, 256, 0, stream>>>(w_fl, wTfl);
    k_transpose_w<64, 64, 1><<<(4096 + 255) / 256, 256, 0, stream>>>(w_sk2, wsk2);
    k_transpose_w<32, 32, 1><<<(1024 + 255) / 256, 256, 0, stream>>>(w_sk1, wsk1);
    k_eff<64, 128><<<(2 * 64 * 128 + 255) / 256, 256, 0, stream>>>(w_d3, eff3);
    k_eff<32, 64><<<(2 * 32 * 64 + 255) / 256, 256, 0, stream>>>(w_d2, eff2);
    k_eff<32, 32><<<(2 * 32 * 32 + 255) / 256, 256, 0, stream>>>(w_d1, eff1);

    for (int t = 0; t < TSTEPS; ++t) {
        float inv = 1.0f / (float)(t + 1);
        // e1 -> s1p (padded u8), 1024 blocks (4/CU) -> MINW 4
        k_e1<16><<<dim3(8, 8, NB * 2), 256, 0, stream>>>(x, wTe1, b_e1, me1, mn1, s1p, t, inv);
        // e2: s1p -> s2p, 1024 blocks (4/CU) -> MINW 4
        k_enc2<32, 64, 64, 8, true, 132, 66, 68, 4><<<dim3(1, 16, NB * 8), 256, 0, stream>>>(
            s1p, wTe2, b_e2, me2, mn2, s2p, inv);
        // e3: s2p -> s3p, 512 blocks (2/CU) -> MINW 2
        k_enc2<64, 128, 32, 8, false, 68, 34, 36, 2><<<dim3(1, 4, NB * 16), 256, 0, stream>>>(
            s2p, wTe3, b_e3, me3, (float*)nullptr, s3p, 0.f);
        // d3: s3p -> d3fp (padded float), 512 blocks (2/CU)
        k_dec3<<<dim3(1, 2, NB * 2 * 16), 256, 0, stream>>>(
            s3p, eff3, b_d3, md3, mn2, wsk2, d3fp);
        // d2: d3fp -> d2fp (padded float), 512 blocks (2/CU) -> MINW 2
        k_decf<64, 32, 64, 8, true, false, 68, 130, 132, 2><<<dim3(1, 8, NB * 2 * 4), 256, 0, stream>>>(
            d3fp, eff2, b_d2, md2, mn1, wsk1, d2fp, 1);
        // d1: d2fp -> d1u (u8, t=9 only), 2048 blocks (8/CU) -> MINW 4
        k_decf<32, 32, 128, 8, false, true, 132, 0, 0, 4><<<dim3(2, 16, NB * 2 * 4), 256, 0, stream>>>(
            d2fp, eff1, b_d1, md1, (const float*)nullptr, (const float*)nullptr, d1u,
            (t == TSTEPS - 1) ? 1 : 0);
    }
    k_flow<<<dim3(16, 16, NB), 256, 0, stream>>>(d1u, wTfl, b_fl, (float*)d_out);
}